// Round 5
// baseline (422.378 us; speedup 1.0000x reference)
//
#include <hip/hip_runtime.h>

#define N_NODES 50000
#define N_EDGES 400000
#define E_TOT   (N_EDGES + N_NODES)   // 450000, self-loops appended
#define IN_C 128
#define HID  512
#define OUT2 64
#define NEG_SLOPE 0.2f

typedef short bf16x8 __attribute__((ext_vector_type(8)));
typedef float f32x4  __attribute__((ext_vector_type(4)));

__device__ __forceinline__ float wave_sum(float v) {
#pragma unroll
  for (int o = 32; o > 0; o >>= 1) v += __shfl_xor(v, o, 64);
  return v;
}
__device__ __forceinline__ int wave_sum_i(int v) {
#pragma unroll
  for (int o = 32; o > 0; o >>= 1) v += __shfl_xor(v, o, 64);
  return v;
}
__device__ __forceinline__ float wave_max(float v) {
#pragma unroll
  for (int o = 32; o > 0; o >>= 1) v = fmaxf(v, __shfl_xor(v, o, 64));
  return v;
}
__device__ __forceinline__ float leaky(float t) {
  return (t > 0.f) ? t : NEG_SLOPE * t;
}

// fp32 -> bf16 (RNE) and hi/lo split: x ~= hi + lo, |err| <= 2^-18 |x|
__device__ __forceinline__ unsigned short bf16_rne(float x) {
  unsigned u = __float_as_uint(x);
  u += 0x7fffu + ((u >> 16) & 1u);
  return (unsigned short)(u >> 16);
}
__device__ __forceinline__ void split_bf16(float x, unsigned short& h, unsigned short& l) {
  h = bf16_rne(x);
  float hf = __uint_as_float(((unsigned)h) << 16);
  l = bf16_rne(x - hf);
}

// src/dst of logical edge e (e >= N_EDGES are self-loops)
__device__ __forceinline__ int esrc(const int* __restrict__ ei, int e) {
  return (e < N_EDGES) ? ei[e] : (e - N_EDGES);
}
__device__ __forceinline__ int edst(const int* __restrict__ ei, int e) {
  return (e < N_EDGES) ? ei[N_EDGES + e] : (e - N_EDGES);
}

// ---- CSR build -------------------------------------------------------------
__global__ void count_deg(const int* __restrict__ ei, int* __restrict__ deg) {
  int e = blockIdx.x * blockDim.x + threadIdx.x;
  if (e >= E_TOT) return;
  atomicAdd(&deg[edst(ei, e)], 1);
}

__global__ void scanA(const int* __restrict__ deg, int* __restrict__ bsum) {
  __shared__ int ws[16];
  int t = threadIdx.x, lane = t & 63, w = t >> 6;
  int i = blockIdx.x * 1024 + t;
  int v = (i < N_NODES) ? deg[i] : 0;
  int s = wave_sum_i(v);
  if (lane == 0) ws[w] = s;
  __syncthreads();
  if (t == 0) {
    int tot = 0;
#pragma unroll
    for (int k = 0; k < 16; k++) tot += ws[k];
    bsum[blockIdx.x] = tot;
  }
}

__global__ void scanB(const int* __restrict__ bsum, int* __restrict__ boff, int nb) {
  int lane = threadIdx.x;  // 64 threads
  int v = (lane < nb) ? bsum[lane] : 0;
  int sc = v;
#pragma unroll
  for (int off = 1; off < 64; off <<= 1) {
    int u = __shfl_up(sc, off, 64);
    if (lane >= off) sc += u;
  }
  if (lane < nb) boff[lane] = sc - v;  // exclusive
}

__global__ void scanC(const int* __restrict__ deg, const int* __restrict__ boff,
                      int* __restrict__ row_ptr) {
  __shared__ int ws[16];
  int t = threadIdx.x, lane = t & 63, w = t >> 6;
  int i = blockIdx.x * 1024 + t;
  int v = (i < N_NODES) ? deg[i] : 0;
  int sc = v;
#pragma unroll
  for (int off = 1; off < 64; off <<= 1) {
    int u = __shfl_up(sc, off, 64);
    if (lane >= off) sc += u;
  }
  if (lane == 63) ws[w] = sc;
  __syncthreads();
  if (w == 0 && lane < 16) {
    int u = ws[lane];
#pragma unroll
    for (int off = 1; off < 16; off <<= 1) {
      int uu = __shfl_up(u, off, 64);
      if (lane >= off) u += uu;
    }
    ws[lane] = u;
  }
  __syncthreads();
  int excl = ((w > 0) ? ws[w - 1] : 0) + boff[blockIdx.x];
  if (i < N_NODES) row_ptr[i + 1] = sc + excl;
  if (blockIdx.x == 0 && t == 0) row_ptr[0] = 0;
}

__global__ void fill_csr(const int* __restrict__ ei, const int* __restrict__ row_ptr,
                         int* __restrict__ cursor, int* __restrict__ csr_src) {
  int e = blockIdx.x * blockDim.x + threadIdx.x;
  if (e >= E_TOT) return;
  int d = edst(ei, e);
  int pos = atomicAdd(&cursor[d], 1);
  csr_src[row_ptr[d] + pos] = esrc(ei, e);
}

// ---- weight prep: transpose + bf16 hi/lo split -----------------------------
// W1T[c][k] (c<512,k<128) from W1[k][c]
__global__ void prep_w1(const float* __restrict__ W1, unsigned short* __restrict__ W1Th,
                        unsigned short* __restrict__ W1Tl) {
  int t = blockIdx.x * 256 + threadIdx.x;
  if (t >= HID * IN_C) return;
  int c = t >> 7, k = t & 127;
  unsigned short h, l;
  split_bf16(W1[(size_t)k * HID + c], h, l);
  W1Th[t] = h; W1Tl[t] = l;
}
// W2T[c][k2] (c<64,k2<512) from W2[k2][c]
__global__ void prep_w2(const float* __restrict__ W2, unsigned short* __restrict__ W2Th,
                        unsigned short* __restrict__ W2Tl) {
  int t = blockIdx.x * 256 + threadIdx.x;
  if (t >= OUT2 * HID) return;
  int c = t >> 9, k = t & 511;
  unsigned short h, l;
  split_bf16(W2[(size_t)k * OUT2 + c], h, l);
  W2Th[t] = h; W2Tl[t] = l;
}

// ---- layer-1 score vectors: w1s = W1 @ a1_src, w1d = W1 @ a1_dst ----------
__global__ void matvec_w1(const float* __restrict__ W1, const float* __restrict__ a1s,
                          const float* __restrict__ a1d, float* __restrict__ w1s,
                          float* __restrict__ w1d) {
  int wid = (blockIdx.x * blockDim.x + threadIdx.x) >> 6;
  int lane = threadIdx.x & 63;
  if (wid >= IN_C) return;
  const float* row = W1 + (size_t)wid * HID;
  float s = 0.f, d = 0.f;
#pragma unroll
  for (int j0 = 0; j0 < HID; j0 += 64) {
    float w = row[j0 + lane];
    s += w * a1s[j0 + lane];
    d += w * a1d[j0 + lane];
  }
  s = wave_sum(s); d = wave_sum(d);
  if (lane == 0) { w1s[wid] = s; w1d[wid] = d; }
}

// alpha_s[i] = x[i].w1s ; alpha_d[i] = x[i].w1d  (one wave per node, float2)
__global__ void node_scores128(const float* __restrict__ x, const float* __restrict__ ws,
                               const float* __restrict__ wd, float* __restrict__ as_,
                               float* __restrict__ ad_) {
  int wid = (blockIdx.x * blockDim.x + threadIdx.x) >> 6;
  int lane = threadIdx.x & 63;
  if (wid >= N_NODES) return;
  float2 v = ((const float2*)(x + (size_t)wid * IN_C))[lane];
  float2 w1 = ((const float2*)ws)[lane];
  float2 w2 = ((const float2*)wd)[lane];
  float s = wave_sum(v.x * w1.x + v.y * w1.y);
  float d = wave_sum(v.x * w2.x + v.y * w2.y);
  if (lane == 0) { as_[wid] = s; ad_[wid] = d; }
}

// ---- fused segment-softmax + aggregation, layer 1 (128 ch, input space) ----
__global__ void sm_agg1(const int* __restrict__ row_ptr, const int* __restrict__ csr_src,
                        const float* __restrict__ as_, const float* __restrict__ ad_,
                        const float* __restrict__ x, float* __restrict__ xa) {
  int wid = (blockIdx.x * blockDim.x + threadIdx.x) >> 6;
  int lane = threadIdx.x & 63;
  if (wid >= N_NODES) return;
  int beg = row_ptr[wid], end = row_ptr[wid + 1];
  int deg = end - beg;
  float adv = ad_[wid];
  float2 acc = make_float2(0.f, 0.f);
  if (deg <= 64) {
    int s = 0; float sc = -3.4e38f;
    if (lane < deg) { s = csr_src[beg + lane]; sc = leaky(as_[s] + adv); }
    float m = wave_max(sc);
    float ex = (lane < deg) ? __expf(sc - m) : 0.f;
    float sum = wave_sum(ex);
    float a = ex / sum;
    for (int kk = 0; kk < deg; kk++) {
      float w = __shfl(a, kk, 64);
      int sv = __shfl(s, kk, 64);
      float2 r = ((const float2*)(x + (size_t)sv * IN_C))[lane];
      acc.x += w * r.x; acc.y += w * r.y;
    }
  } else {  // fallback (kept for correctness on any graph)
    float m = -3.4e38f;
    for (int k = beg + lane; k < end; k += 64)
      m = fmaxf(m, leaky(as_[csr_src[k]] + adv));
    m = wave_max(m);
    float sum = 0.f;
    for (int k = beg + lane; k < end; k += 64)
      sum += __expf(leaky(as_[csr_src[k]] + adv) - m);
    sum = wave_sum(sum);
    float inv = 1.f / sum;
    for (int k = beg; k < end; k++) {
      int sv = csr_src[k];
      float w = __expf(leaky(as_[sv] + adv) - m) * inv;
      float2 r = ((const float2*)(x + (size_t)sv * IN_C))[lane];
      acc.x += w * r.x; acc.y += w * r.y;
    }
  }
  ((float2*)(xa + (size_t)wid * IN_C))[lane] = acc;
}

// ---- fused gemm1(relu) + gemm2 + layer-2 node scores, bf16-split MFMA ------
// h2 = relu(xa@W1+b1)@W2 via 3-term hi/lo split (AhBh + AlBh + AhBl).
// k-distribution per lane chosen as k = G*8+e for BOTH operands: any
// consistent k-permutation leaves the contraction invariant. C/D layout
// (HW-verified m89): col = lane&15, row = (lane>>4)*4 + reg.
__launch_bounds__(256)
__global__ void fused_gemm_mfma(const float* __restrict__ xa,
                                const unsigned short* __restrict__ W1Th,
                                const unsigned short* __restrict__ W1Tl,
                                const float* __restrict__ b1,
                                const unsigned short* __restrict__ W2Th,
                                const unsigned short* __restrict__ W2Tl,
                                const float* __restrict__ a2s, const float* __restrict__ a2d,
                                float* __restrict__ h2, float* __restrict__ as2,
                                float* __restrict__ ad2) {
  __shared__ unsigned short Ah[64][128];  // 16KB, k-index XOR ((row&7)<<3)
  __shared__ unsigned short Al[64][128];  // 16KB
  __shared__ unsigned int   TS[64][64];   // 16KB, out1 slab packed hi|lo<<16, col XOR ((row&7)<<2)
  int m0 = blockIdx.x * 64;
  int t = threadIdx.x;
  int w = t >> 6;        // wave id = 16-row M-stripe
  int l = t & 63;
  int lr = l & 15;       // row/col within 16-tile
  int G  = l >> 4;       // k-group

  // ---- stage A: xa fp32 -> hi/lo bf16, swizzled ----
#pragma unroll
  for (int j = 0; j < 8; j++) {
    int idx = t + j * 256;           // 2048 float4 slots
    int row = idx >> 5, c4 = idx & 31;
    int gr = m0 + row;
    float4 v = make_float4(0.f, 0.f, 0.f, 0.f);
    if (gr < N_NODES) v = *(const float4*)(xa + (size_t)gr * IN_C + c4 * 4);
    int k0 = (c4 * 4) ^ ((row & 7) << 3);   // XOR bits 3-5: 4-block stays contiguous
    unsigned short h0, l0, h1, l1, h2_, l2_, h3, l3;
    split_bf16(v.x, h0, l0); split_bf16(v.y, h1, l1);
    split_bf16(v.z, h2_, l2_); split_bf16(v.w, h3, l3);
    *(uint2*)&Ah[row][k0] = make_uint2((unsigned)h0 | ((unsigned)h1 << 16),
                                       (unsigned)h2_ | ((unsigned)h3 << 16));
    *(uint2*)&Al[row][k0] = make_uint2((unsigned)l0 | ((unsigned)l1 << 16),
                                       (unsigned)l2_ | ((unsigned)l3 << 16));
  }
  __syncthreads();

  f32x4 acc2[4];
#pragma unroll
  for (int n = 0; n < 4; n++) acc2[n] = (f32x4){0.f, 0.f, 0.f, 0.f};

  int rowA = w * 16 + lr;
  int swA = (rowA & 7) << 3;
  int sw2 = (rowA & 7) << 2;

  for (int jt = 0; jt < 8; jt++) {
    // --- gemm1 slab: cols jt*64 + n*16 + lr, K = 128 ---
    f32x4 acc1[4];
#pragma unroll
    for (int n = 0; n < 4; n++) acc1[n] = (f32x4){0.f, 0.f, 0.f, 0.f};
#pragma unroll
    for (int ks = 0; ks < 4; ks++) {
      int kb = (ks * 32 + G * 8) ^ swA;
      bf16x8 a_h = *(const bf16x8*)&Ah[rowA][kb];
      bf16x8 a_l = *(const bf16x8*)&Al[rowA][kb];
#pragma unroll
      for (int n = 0; n < 4; n++) {
        size_t off = (size_t)(jt * 64 + n * 16 + lr) * IN_C + ks * 32 + G * 8;
        bf16x8 b_h = *(const bf16x8*)(W1Th + off);
        bf16x8 b_l = *(const bf16x8*)(W1Tl + off);
        acc1[n] = __builtin_amdgcn_mfma_f32_16x16x32_bf16(a_h, b_h, acc1[n], 0, 0, 0);
        acc1[n] = __builtin_amdgcn_mfma_f32_16x16x32_bf16(a_l, b_h, acc1[n], 0, 0, 0);
        acc1[n] = __builtin_amdgcn_mfma_f32_16x16x32_bf16(a_h, b_l, acc1[n], 0, 0, 0);
      }
    }
    // --- epilogue: bias + relu, split, write TS (packed hi|lo) ---
    __syncthreads();                 // previous jt's TS readers done
#pragma unroll
    for (int n = 0; n < 4; n++) {
      float bv = b1[jt * 64 + n * 16 + lr];
#pragma unroll
      for (int r = 0; r < 4; r++) {
        float vv = fmaxf(acc1[n][r] + bv, 0.f);
        unsigned short hh, ll;
        split_bf16(vv, hh, ll);
        int rowL = w * 16 + G * 4 + r;          // C/D: row = G*4+r within tile
        int colS = (n * 16 + lr) ^ ((rowL & 7) << 2);
        TS[rowL][colS] = (unsigned)hh | ((unsigned)ll << 16);
      }
    }
    __syncthreads();
    // --- gemm2 partial: acc2 += out1_slab @ W2[jt*64 .. jt*64+63, :] ---
#pragma unroll
    for (int ks = 0; ks < 2; ks++) {
      int kl = ks * 32 + G * 8;
      uint4 q0 = *(const uint4*)&TS[rowA][(kl + 0) ^ sw2];
      uint4 q1 = *(const uint4*)&TS[rowA][(kl + 4) ^ sw2];
      bf16x8 a2h, a2l;
      a2h[0] = (short)(q0.x & 0xffff); a2l[0] = (short)(q0.x >> 16);
      a2h[1] = (short)(q0.y & 0xffff); a2l[1] = (short)(q0.y >> 16);
      a2h[2] = (short)(q0.z & 0xffff); a2l[2] = (short)(q0.z >> 16);
      a2h[3] = (short)(q0.w & 0xffff); a2l[3] = (short)(q0.w >> 16);
      a2h[4] = (short)(q1.x & 0xffff); a2l[4] = (short)(q1.x >> 16);
      a2h[5] = (short)(q1.y & 0xffff); a2l[5] = (short)(q1.y >> 16);
      a2h[6] = (short)(q1.z & 0xffff); a2l[6] = (short)(q1.z >> 16);
      a2h[7] = (short)(q1.w & 0xffff); a2l[7] = (short)(q1.w >> 16);
#pragma unroll
      for (int n = 0; n < 4; n++) {
        size_t off = (size_t)(n * 16 + lr) * HID + jt * 64 + kl;
        bf16x8 b_h = *(const bf16x8*)(W2Th + off);
        bf16x8 b_l = *(const bf16x8*)(W2Tl + off);
        acc2[n] = __builtin_amdgcn_mfma_f32_16x16x32_bf16(a2h, b_h, acc2[n], 0, 0, 0);
        acc2[n] = __builtin_amdgcn_mfma_f32_16x16x32_bf16(a2l, b_h, acc2[n], 0, 0, 0);
        acc2[n] = __builtin_amdgcn_mfma_f32_16x16x32_bf16(a2h, b_l, acc2[n], 0, 0, 0);
      }
    }
  }

  // ---- epilogue: h2 write + fused layer-2 node scores ----
#pragma unroll
  for (int r = 0; r < 4; r++) {
    int grow = m0 + w * 16 + G * 4 + r;
    if (grow < N_NODES) {
#pragma unroll
      for (int n = 0; n < 4; n++)
        h2[(size_t)grow * OUT2 + n * 16 + lr] = acc2[n][r];
    }
    float sp = 0.f, dp = 0.f;
#pragma unroll
    for (int n = 0; n < 4; n++) {
      float v = acc2[n][r];
      sp += v * a2s[n * 16 + lr];
      dp += v * a2d[n * 16 + lr];
    }
#pragma unroll
    for (int o = 1; o < 16; o <<= 1) {
      sp += __shfl_xor(sp, o, 64);
      dp += __shfl_xor(dp, o, 64);
    }
    if (lr == 0 && grow < N_NODES) { as2[grow] = sp; ad2[grow] = dp; }
  }
}

// ---- fused layer-2 softmax + aggregation + relu + FC head ------------------
__global__ void sm_agg2_final(const int* __restrict__ row_ptr, const int* __restrict__ csr_src,
                              const float* __restrict__ as_, const float* __restrict__ ad_,
                              const float* __restrict__ h2, const float* __restrict__ b2,
                              const float* __restrict__ fcW, const float* __restrict__ fcb,
                              float* __restrict__ out) {
  int wid = (blockIdx.x * blockDim.x + threadIdx.x) >> 6;
  int lane = threadIdx.x & 63;
  if (wid >= N_NODES) return;
  int beg = row_ptr[wid], end = row_ptr[wid + 1];
  int deg = end - beg;
  float adv = ad_[wid];
  float acc = 0.f;
  if (deg <= 64) {
    int s = 0; float sc = -3.4e38f;
    if (lane < deg) { s = csr_src[beg + lane]; sc = leaky(as_[s] + adv); }
    float m = wave_max(sc);
    float ex = (lane < deg) ? __expf(sc - m) : 0.f;
    float sum = wave_sum(ex);
    float a = ex / sum;
    for (int kk = 0; kk < deg; kk++) {
      float w = __shfl(a, kk, 64);
      int sv = __shfl(s, kk, 64);
      acc += w * h2[(size_t)sv * OUT2 + lane];
    }
  } else {
    float m = -3.4e38f;
    for (int k = beg + lane; k < end; k += 64)
      m = fmaxf(m, leaky(as_[csr_src[k]] + adv));
    m = wave_max(m);
    float sum = 0.f;
    for (int k = beg + lane; k < end; k += 64)
      sum += __expf(leaky(as_[csr_src[k]] + adv) - m);
    sum = wave_sum(sum);
    float inv = 1.f / sum;
    for (int k = beg; k < end; k++) {
      int sv = csr_src[k];
      float w = __expf(leaky(as_[sv] + adv) - m) * inv;
      acc += w * h2[(size_t)sv * OUT2 + lane];
    }
  }
  float v = fmaxf(acc + b2[lane], 0.f);
  float2 fw = ((const float2*)fcW)[lane];
  float f0 = wave_sum(v * fw.x);
  float f1 = wave_sum(v * fw.y);
  if (lane == 0) {
    out[(size_t)wid * 2 + 0] = f0 + fcb[0];
    out[(size_t)wid * 2 + 1] = f1 + fcb[1];
  }
}

extern "C" void kernel_launch(void* const* d_in, const int* in_sizes, int n_in,
                              void* d_out, int out_size, void* d_ws, size_t ws_size,
                              hipStream_t stream) {
  const float* x    = (const float*)d_in[0];
  const int*   ei   = (const int*)d_in[1];
  const float* W1   = (const float*)d_in[2];
  const float* a1s  = (const float*)d_in[3];
  const float* a1d  = (const float*)d_in[4];
  const float* b1   = (const float*)d_in[5];
  const float* W2   = (const float*)d_in[6];
  const float* a2s  = (const float*)d_in[7];
  const float* a2d  = (const float*)d_in[8];
  const float* b2   = (const float*)d_in[9];
  const float* fcW  = (const float*)d_in[10];
  const float* fcb  = (const float*)d_in[11];
  float* out = (float*)d_out;

  char* p = (char*)d_ws;
  float* xa    = (float*)p; p += (size_t)N_NODES * IN_C * 4;
  float* h2    = (float*)p; p += (size_t)N_NODES * OUT2 * 4;
  float* as1   = (float*)p; p += (size_t)N_NODES * 4;   // reused for layer-2 scores
  float* ad1   = (float*)p; p += (size_t)N_NODES * 4;
  float* w1s   = (float*)p; p += 256 * 4;
  float* w1d   = (float*)p; p += 256 * 4;
  int* row_ptr = (int*)p;   p += (size_t)(N_NODES + 4) * 4;
  int* deg     = (int*)p;   p += (size_t)N_NODES * 4;   // also reused as cursor
  int* bsum    = (int*)p;   p += 64 * 4;
  int* boff    = (int*)p;   p += 64 * 4;
  int* csr_src = (int*)p;   p += (size_t)E_TOT * 4;
  unsigned short* W1Th = (unsigned short*)p; p += (size_t)HID * IN_C * 2;
  unsigned short* W1Tl = (unsigned short*)p; p += (size_t)HID * IN_C * 2;
  unsigned short* W2Th = (unsigned short*)p; p += (size_t)OUT2 * HID * 2;
  unsigned short* W2Tl = (unsigned short*)p; p += (size_t)OUT2 * HID * 2;

  const int edge_blocks = (E_TOT + 255) / 256;
  const int node_wave_blocks = (N_NODES + 3) / 4;   // 4 waves per 256-thread block
  const int m_tiles = (N_NODES + 63) / 64;
  const int scan_blocks = (N_NODES + 1023) / 1024;  // 49

  // ---- CSR build + weight prep ----
  hipMemsetAsync(deg, 0, (size_t)N_NODES * 4, stream);
  count_deg<<<edge_blocks, 256, 0, stream>>>(ei, deg);
  scanA<<<scan_blocks, 1024, 0, stream>>>(deg, bsum);
  scanB<<<1, 64, 0, stream>>>(bsum, boff, scan_blocks);
  scanC<<<scan_blocks, 1024, 0, stream>>>(deg, boff, row_ptr);
  hipMemsetAsync(deg, 0, (size_t)N_NODES * 4, stream);
  fill_csr<<<edge_blocks, 256, 0, stream>>>(ei, row_ptr, deg, csr_src);
  prep_w1<<<(HID * IN_C + 255) / 256, 256, 0, stream>>>(W1, W1Th, W1Tl);
  prep_w2<<<(OUT2 * HID + 255) / 256, 256, 0, stream>>>(W2, W2Th, W2Tl);

  // ---- layer 1: scores -> fused softmax+aggregate (input space) ----
  matvec_w1<<<(IN_C + 3) / 4, 256, 0, stream>>>(W1, a1s, a1d, w1s, w1d);
  node_scores128<<<node_wave_blocks, 256, 0, stream>>>(x, w1s, w1d, as1, ad1);
  sm_agg1<<<node_wave_blocks, 256, 0, stream>>>(row_ptr, csr_src, as1, ad1, x, xa);

  // ---- fused gemm1+relu+gemm2+layer-2 scores (bf16-split MFMA) ----
  fused_gemm_mfma<<<m_tiles, 256, 0, stream>>>(xa, W1Th, W1Tl, b1, W2Th, W2Tl,
                                               a2s, a2d, h2, as1, ad1);

  // ---- layer 2: fused softmax+aggregate+relu+head ----
  sm_agg2_final<<<node_wave_blocks, 256, 0, stream>>>(row_ptr, csr_src, as1, ad1, h2, b2,
                                                      fcW, fcb, out);
}

// Round 6
// 308.307 us; speedup vs baseline: 1.3700x; 1.3700x over previous
//
#include <hip/hip_runtime.h>

#define N_NODES 50000
#define N_EDGES 400000
#define E_TOT   (N_EDGES + N_NODES)   // 450000, self-loops appended
#define IN_C 128
#define HID  512
#define OUT2 64
#define NEG_SLOPE 0.2f

typedef short bf16x8 __attribute__((ext_vector_type(8)));
typedef float f32x4  __attribute__((ext_vector_type(4)));

__device__ __forceinline__ float wave_sum(float v) {
#pragma unroll
  for (int o = 32; o > 0; o >>= 1) v += __shfl_xor(v, o, 64);
  return v;
}
__device__ __forceinline__ int wave_sum_i(int v) {
#pragma unroll
  for (int o = 32; o > 0; o >>= 1) v += __shfl_xor(v, o, 64);
  return v;
}
__device__ __forceinline__ float wave_max(float v) {
#pragma unroll
  for (int o = 32; o > 0; o >>= 1) v = fmaxf(v, __shfl_xor(v, o, 64));
  return v;
}
__device__ __forceinline__ float leaky(float t) {
  return (t > 0.f) ? t : NEG_SLOPE * t;
}

// fp32 -> bf16 (RNE) and hi/lo split: x ~= hi + lo, |err| <= 2^-18 |x|
__device__ __forceinline__ unsigned short bf16_rne(float x) {
  unsigned u = __float_as_uint(x);
  u += 0x7fffu + ((u >> 16) & 1u);
  return (unsigned short)(u >> 16);
}
__device__ __forceinline__ void split_bf16(float x, unsigned short& h, unsigned short& l) {
  h = bf16_rne(x);
  float hf = __uint_as_float(((unsigned)h) << 16);
  l = bf16_rne(x - hf);
}

// src/dst of logical edge e (e >= N_EDGES are self-loops)
__device__ __forceinline__ int esrc(const int* __restrict__ ei, int e) {
  return (e < N_EDGES) ? ei[e] : (e - N_EDGES);
}
__device__ __forceinline__ int edst(const int* __restrict__ ei, int e) {
  return (e < N_EDGES) ? ei[N_EDGES + e] : (e - N_EDGES);
}

// ---- CSR build -------------------------------------------------------------
__global__ void count_deg(const int* __restrict__ ei, int* __restrict__ deg) {
  int e = blockIdx.x * blockDim.x + threadIdx.x;
  if (e >= E_TOT) return;
  atomicAdd(&deg[edst(ei, e)], 1);
}

__global__ void scanA(const int* __restrict__ deg, int* __restrict__ bsum) {
  __shared__ int ws[16];
  int t = threadIdx.x, lane = t & 63, w = t >> 6;
  int i = blockIdx.x * 1024 + t;
  int v = (i < N_NODES) ? deg[i] : 0;
  int s = wave_sum_i(v);
  if (lane == 0) ws[w] = s;
  __syncthreads();
  if (t == 0) {
    int tot = 0;
#pragma unroll
    for (int k = 0; k < 16; k++) tot += ws[k];
    bsum[blockIdx.x] = tot;
  }
}

__global__ void scanB(const int* __restrict__ bsum, int* __restrict__ boff, int nb) {
  int lane = threadIdx.x;  // 64 threads
  int v = (lane < nb) ? bsum[lane] : 0;
  int sc = v;
#pragma unroll
  for (int off = 1; off < 64; off <<= 1) {
    int u = __shfl_up(sc, off, 64);
    if (lane >= off) sc += u;
  }
  if (lane < nb) boff[lane] = sc - v;  // exclusive
}

__global__ void scanC(const int* __restrict__ deg, const int* __restrict__ boff,
                      int* __restrict__ row_ptr) {
  __shared__ int ws[16];
  int t = threadIdx.x, lane = t & 63, w = t >> 6;
  int i = blockIdx.x * 1024 + t;
  int v = (i < N_NODES) ? deg[i] : 0;
  int sc = v;
#pragma unroll
  for (int off = 1; off < 64; off <<= 1) {
    int u = __shfl_up(sc, off, 64);
    if (lane >= off) sc += u;
  }
  if (lane == 63) ws[w] = sc;
  __syncthreads();
  if (w == 0 && lane < 16) {
    int u = ws[lane];
#pragma unroll
    for (int off = 1; off < 16; off <<= 1) {
      int uu = __shfl_up(u, off, 64);
      if (lane >= off) u += uu;
    }
    ws[lane] = u;
  }
  __syncthreads();
  int excl = ((w > 0) ? ws[w - 1] : 0) + boff[blockIdx.x];
  if (i < N_NODES) row_ptr[i + 1] = sc + excl;
  if (blockIdx.x == 0 && t == 0) row_ptr[0] = 0;
}

__global__ void fill_csr(const int* __restrict__ ei, const int* __restrict__ row_ptr,
                         int* __restrict__ cursor, int* __restrict__ csr_src) {
  int e = blockIdx.x * blockDim.x + threadIdx.x;
  if (e >= E_TOT) return;
  int d = edst(ei, e);
  int pos = atomicAdd(&cursor[d], 1);
  csr_src[row_ptr[d] + pos] = esrc(ei, e);
}

// ---- weight prep: MFMA-fragment-ordered hi/lo bf16 -------------------------
// W1F layout: frag fi = ((jt*4+n)*4+ks), lane l:
//   col = jt*64+n*16+(l&15), k = ks*32+(l>>4)*8 .. +8
//   W1F[((fi*2+hl)*64+l)*8 + e]   (every wave load = base + l*16B, coalesced)
__global__ void prep_w1_frag(const float* __restrict__ W1, unsigned short* __restrict__ W1F) {
  int t = blockIdx.x * 256 + threadIdx.x;   // 8192 lane-tasks
  if (t >= 128 * 64) return;
  int fi = t >> 6, l = t & 63;
  int ks = fi & 3, n = (fi >> 2) & 3, jt = fi >> 4;
  int col = jt * 64 + n * 16 + (l & 15);
  int k0 = ks * 32 + (l >> 4) * 8;
  unsigned short hv[8], lv[8];
#pragma unroll
  for (int e = 0; e < 8; e++)
    split_bf16(W1[(size_t)(k0 + e) * HID + col], hv[e], lv[e]);
  unsigned short* ph = W1F + ((size_t)(fi * 2 + 0) * 64 + l) * 8;
  unsigned short* pl = W1F + ((size_t)(fi * 2 + 1) * 64 + l) * 8;
#pragma unroll
  for (int e = 0; e < 8; e++) { ph[e] = hv[e]; pl[e] = lv[e]; }
}

// W2F layout: frag fi2 = ((jt*2+ks)*4+n), lane l:
//   col = n*16+(l&15), k2 = jt*64+ks*32+(l>>4)*8 .. +8
__global__ void prep_w2_frag(const float* __restrict__ W2, unsigned short* __restrict__ W2F) {
  int t = blockIdx.x * 256 + threadIdx.x;   // 4096 lane-tasks
  if (t >= 64 * 64) return;
  int fi = t >> 6, l = t & 63;
  int n = fi & 3, ks = (fi >> 2) & 1, jt = fi >> 3;
  int col = n * 16 + (l & 15);
  int k0 = jt * 64 + ks * 32 + (l >> 4) * 8;
  unsigned short hv[8], lv[8];
#pragma unroll
  for (int e = 0; e < 8; e++)
    split_bf16(W2[(size_t)(k0 + e) * OUT2 + col], hv[e], lv[e]);
  unsigned short* ph = W2F + ((size_t)(fi * 2 + 0) * 64 + l) * 8;
  unsigned short* pl = W2F + ((size_t)(fi * 2 + 1) * 64 + l) * 8;
#pragma unroll
  for (int e = 0; e < 8; e++) { ph[e] = hv[e]; pl[e] = lv[e]; }
}

// ---- layer-1 score vectors: w1s = W1 @ a1_src, w1d = W1 @ a1_dst ----------
__global__ void matvec_w1(const float* __restrict__ W1, const float* __restrict__ a1s,
                          const float* __restrict__ a1d, float* __restrict__ w1s,
                          float* __restrict__ w1d) {
  int wid = (blockIdx.x * blockDim.x + threadIdx.x) >> 6;
  int lane = threadIdx.x & 63;
  if (wid >= IN_C) return;
  const float* row = W1 + (size_t)wid * HID;
  float s = 0.f, d = 0.f;
#pragma unroll
  for (int j0 = 0; j0 < HID; j0 += 64) {
    float w = row[j0 + lane];
    s += w * a1s[j0 + lane];
    d += w * a1d[j0 + lane];
  }
  s = wave_sum(s); d = wave_sum(d);
  if (lane == 0) { w1s[wid] = s; w1d[wid] = d; }
}

// alpha_s[i] = x[i].w1s ; alpha_d[i] = x[i].w1d  (one wave per node, float2)
__global__ void node_scores128(const float* __restrict__ x, const float* __restrict__ ws,
                               const float* __restrict__ wd, float* __restrict__ as_,
                               float* __restrict__ ad_) {
  int wid = (blockIdx.x * blockDim.x + threadIdx.x) >> 6;
  int lane = threadIdx.x & 63;
  if (wid >= N_NODES) return;
  float2 v = ((const float2*)(x + (size_t)wid * IN_C))[lane];
  float2 w1 = ((const float2*)ws)[lane];
  float2 w2 = ((const float2*)wd)[lane];
  float s = wave_sum(v.x * w1.x + v.y * w1.y);
  float d = wave_sum(v.x * w2.x + v.y * w2.y);
  if (lane == 0) { as_[wid] = s; ad_[wid] = d; }
}

// ---- fused segment-softmax + aggregation, layer 1 (128 ch, input space) ----
__global__ void sm_agg1(const int* __restrict__ row_ptr, const int* __restrict__ csr_src,
                        const float* __restrict__ as_, const float* __restrict__ ad_,
                        const float* __restrict__ x, float* __restrict__ xa) {
  int wid = (blockIdx.x * blockDim.x + threadIdx.x) >> 6;
  int lane = threadIdx.x & 63;
  if (wid >= N_NODES) return;
  int beg = row_ptr[wid], end = row_ptr[wid + 1];
  int deg = end - beg;
  float adv = ad_[wid];
  float2 acc = make_float2(0.f, 0.f);
  if (deg <= 64) {
    int s = 0; float sc = -3.4e38f;
    if (lane < deg) { s = csr_src[beg + lane]; sc = leaky(as_[s] + adv); }
    float m = wave_max(sc);
    float ex = (lane < deg) ? __expf(sc - m) : 0.f;
    float sum = wave_sum(ex);
    float a = ex / sum;
    for (int kk = 0; kk < deg; kk++) {
      float w = __shfl(a, kk, 64);
      int sv = __shfl(s, kk, 64);
      float2 r = ((const float2*)(x + (size_t)sv * IN_C))[lane];
      acc.x += w * r.x; acc.y += w * r.y;
    }
  } else {  // fallback (kept for correctness on any graph)
    float m = -3.4e38f;
    for (int k = beg + lane; k < end; k += 64)
      m = fmaxf(m, leaky(as_[csr_src[k]] + adv));
    m = wave_max(m);
    float sum = 0.f;
    for (int k = beg + lane; k < end; k += 64)
      sum += __expf(leaky(as_[csr_src[k]] + adv) - m);
    sum = wave_sum(sum);
    float inv = 1.f / sum;
    for (int k = beg; k < end; k++) {
      int sv = csr_src[k];
      float w = __expf(leaky(as_[sv] + adv) - m) * inv;
      float2 r = ((const float2*)(x + (size_t)sv * IN_C))[lane];
      acc.x += w * r.x; acc.y += w * r.y;
    }
  }
  ((float2*)(xa + (size_t)wid * IN_C))[lane] = acc;
}

// ---- fused gemm1(relu) + gemm2 + layer-2 node scores, bf16-split MFMA ------
// B operands pre-packed in fragment order (coalesced base+lane*16B loads);
// A fragments hoisted to registers once per wave (jt-invariant).
__launch_bounds__(256, 2)
__global__ void fused_gemm_mfma(const float* __restrict__ xa,
                                const unsigned short* __restrict__ W1F,
                                const float* __restrict__ b1,
                                const unsigned short* __restrict__ W2F,
                                const float* __restrict__ a2s, const float* __restrict__ a2d,
                                float* __restrict__ h2, float* __restrict__ as2,
                                float* __restrict__ ad2) {
  __shared__ unsigned short Ah[64][128];  // 16KB, k-index XOR ((row&7)<<3)
  __shared__ unsigned short Al[64][128];  // 16KB
  __shared__ unsigned int   TS[64][64];   // 16KB, out1 slab packed hi|lo<<16, col XOR ((row&7)<<2)
  int m0 = blockIdx.x * 64;
  int t = threadIdx.x;
  int w = t >> 6;        // wave id = 16-row M-stripe
  int l = t & 63;
  int lr = l & 15;       // row/col within 16-tile
  int G  = l >> 4;       // k-group

  // ---- stage A: xa fp32 -> hi/lo bf16, swizzled ----
#pragma unroll
  for (int j = 0; j < 8; j++) {
    int idx = t + j * 256;           // 2048 float4 slots
    int row = idx >> 5, c4 = idx & 31;
    int gr = m0 + row;
    float4 v = make_float4(0.f, 0.f, 0.f, 0.f);
    if (gr < N_NODES) v = *(const float4*)(xa + (size_t)gr * IN_C + c4 * 4);
    int k0 = (c4 * 4) ^ ((row & 7) << 3);   // XOR bits 3-5: 4-block stays contiguous
    unsigned short h0, l0, h1, l1, h2_, l2_, h3, l3;
    split_bf16(v.x, h0, l0); split_bf16(v.y, h1, l1);
    split_bf16(v.z, h2_, l2_); split_bf16(v.w, h3, l3);
    *(uint2*)&Ah[row][k0] = make_uint2((unsigned)h0 | ((unsigned)h1 << 16),
                                       (unsigned)h2_ | ((unsigned)h3 << 16));
    *(uint2*)&Al[row][k0] = make_uint2((unsigned)l0 | ((unsigned)l1 << 16),
                                       (unsigned)l2_ | ((unsigned)l3 << 16));
  }
  __syncthreads();

  int rowA = w * 16 + lr;
  int swA = (rowA & 7) << 3;
  int sw2 = (rowA & 7) << 2;

  // ---- hoist A fragments (jt-invariant): full K=128, hi+lo -> 32 VGPRs ----
  bf16x8 aFh[4], aFl[4];
#pragma unroll
  for (int ks = 0; ks < 4; ks++) {
    int kb = (ks * 32 + G * 8) ^ swA;
    aFh[ks] = *(const bf16x8*)&Ah[rowA][kb];
    aFl[ks] = *(const bf16x8*)&Al[rowA][kb];
  }

  const bf16x8* W1Fv = (const bf16x8*)W1F;
  const bf16x8* W2Fv = (const bf16x8*)W2F;

  f32x4 acc2[4];
#pragma unroll
  for (int n = 0; n < 4; n++) acc2[n] = (f32x4){0.f, 0.f, 0.f, 0.f};

  for (int jt = 0; jt < 8; jt++) {
    // --- gemm1 slab: cols jt*64 + n*16 + lr, K = 128 ---
    f32x4 acc1[4];
#pragma unroll
    for (int n = 0; n < 4; n++) acc1[n] = (f32x4){0.f, 0.f, 0.f, 0.f};
#pragma unroll
    for (int ks = 0; ks < 4; ks++) {
#pragma unroll
      for (int n = 0; n < 4; n++) {
        int fi = (jt * 4 + n) * 4 + ks;
        bf16x8 b_h = W1Fv[(size_t)(fi * 2 + 0) * 64 + l];
        bf16x8 b_l = W1Fv[(size_t)(fi * 2 + 1) * 64 + l];
        acc1[n] = __builtin_amdgcn_mfma_f32_16x16x32_bf16(aFh[ks], b_h, acc1[n], 0, 0, 0);
        acc1[n] = __builtin_amdgcn_mfma_f32_16x16x32_bf16(aFl[ks], b_h, acc1[n], 0, 0, 0);
        acc1[n] = __builtin_amdgcn_mfma_f32_16x16x32_bf16(aFh[ks], b_l, acc1[n], 0, 0, 0);
      }
    }
    // --- epilogue: bias + relu, split, write TS (packed hi|lo) ---
    __syncthreads();                 // previous jt's TS readers done
#pragma unroll
    for (int n = 0; n < 4; n++) {
      float bv = b1[jt * 64 + n * 16 + lr];
#pragma unroll
      for (int r = 0; r < 4; r++) {
        float vv = fmaxf(acc1[n][r] + bv, 0.f);
        unsigned short hh, ll;
        split_bf16(vv, hh, ll);
        int rowL = w * 16 + G * 4 + r;          // C/D: row = G*4+r within tile
        int colS = (n * 16 + lr) ^ ((rowL & 7) << 2);
        TS[rowL][colS] = (unsigned)hh | ((unsigned)ll << 16);
      }
    }
    __syncthreads();
    // --- gemm2 partial: acc2 += out1_slab @ W2[jt*64 .. jt*64+63, :] ---
#pragma unroll
    for (int ks = 0; ks < 2; ks++) {
      int kl = ks * 32 + G * 8;
      uint4 q0 = *(const uint4*)&TS[rowA][(kl + 0) ^ sw2];
      uint4 q1 = *(const uint4*)&TS[rowA][(kl + 4) ^ sw2];
      bf16x8 a2h, a2l;
      a2h[0] = (short)(q0.x & 0xffff); a2l[0] = (short)(q0.x >> 16);
      a2h[1] = (short)(q0.y & 0xffff); a2l[1] = (short)(q0.y >> 16);
      a2h[2] = (short)(q0.z & 0xffff); a2l[2] = (short)(q0.z >> 16);
      a2h[3] = (short)(q0.w & 0xffff); a2l[3] = (short)(q0.w >> 16);
      a2h[4] = (short)(q1.x & 0xffff); a2l[4] = (short)(q1.x >> 16);
      a2h[5] = (short)(q1.y & 0xffff); a2l[5] = (short)(q1.y >> 16);
      a2h[6] = (short)(q1.z & 0xffff); a2l[6] = (short)(q1.z >> 16);
      a2h[7] = (short)(q1.w & 0xffff); a2l[7] = (short)(q1.w >> 16);
#pragma unroll
      for (int n = 0; n < 4; n++) {
        int fi2 = (jt * 2 + ks) * 4 + n;
        bf16x8 b_h = W2Fv[(size_t)(fi2 * 2 + 0) * 64 + l];
        bf16x8 b_l = W2Fv[(size_t)(fi2 * 2 + 1) * 64 + l];
        acc2[n] = __builtin_amdgcn_mfma_f32_16x16x32_bf16(a2h, b_h, acc2[n], 0, 0, 0);
        acc2[n] = __builtin_amdgcn_mfma_f32_16x16x32_bf16(a2l, b_h, acc2[n], 0, 0, 0);
        acc2[n] = __builtin_amdgcn_mfma_f32_16x16x32_bf16(a2h, b_l, acc2[n], 0, 0, 0);
      }
    }
  }

  // ---- epilogue: h2 write + fused layer-2 node scores ----
#pragma unroll
  for (int r = 0; r < 4; r++) {
    int grow = m0 + w * 16 + G * 4 + r;
    if (grow < N_NODES) {
#pragma unroll
      for (int n = 0; n < 4; n++)
        h2[(size_t)grow * OUT2 + n * 16 + lr] = acc2[n][r];
    }
    float sp = 0.f, dp = 0.f;
#pragma unroll
    for (int n = 0; n < 4; n++) {
      float v = acc2[n][r];
      sp += v * a2s[n * 16 + lr];
      dp += v * a2d[n * 16 + lr];
    }
#pragma unroll
    for (int o = 1; o < 16; o <<= 1) {
      sp += __shfl_xor(sp, o, 64);
      dp += __shfl_xor(dp, o, 64);
    }
    if (lr == 0 && grow < N_NODES) { as2[grow] = sp; ad2[grow] = dp; }
  }
}

// ---- fused layer-2 softmax + aggregation + relu + FC head ------------------
__global__ void sm_agg2_final(const int* __restrict__ row_ptr, const int* __restrict__ csr_src,
                              const float* __restrict__ as_, const float* __restrict__ ad_,
                              const float* __restrict__ h2, const float* __restrict__ b2,
                              const float* __restrict__ fcW, const float* __restrict__ fcb,
                              float* __restrict__ out) {
  int wid = (blockIdx.x * blockDim.x + threadIdx.x) >> 6;
  int lane = threadIdx.x & 63;
  if (wid >= N_NODES) return;
  int beg = row_ptr[wid], end = row_ptr[wid + 1];
  int deg = end - beg;
  float adv = ad_[wid];
  float acc = 0.f;
  if (deg <= 64) {
    int s = 0; float sc = -3.4e38f;
    if (lane < deg) { s = csr_src[beg + lane]; sc = leaky(as_[s] + adv); }
    float m = wave_max(sc);
    float ex = (lane < deg) ? __expf(sc - m) : 0.f;
    float sum = wave_sum(ex);
    float a = ex / sum;
    for (int kk = 0; kk < deg; kk++) {
      float w = __shfl(a, kk, 64);
      int sv = __shfl(s, kk, 64);
      acc += w * h2[(size_t)sv * OUT2 + lane];
    }
  } else {
    float m = -3.4e38f;
    for (int k = beg + lane; k < end; k += 64)
      m = fmaxf(m, leaky(as_[csr_src[k]] + adv));
    m = wave_max(m);
    float sum = 0.f;
    for (int k = beg + lane; k < end; k += 64)
      sum += __expf(leaky(as_[csr_src[k]] + adv) - m);
    sum = wave_sum(sum);
    float inv = 1.f / sum;
    for (int k = beg; k < end; k++) {
      int sv = csr_src[k];
      float w = __expf(leaky(as_[sv] + adv) - m) * inv;
      acc += w * h2[(size_t)sv * OUT2 + lane];
    }
  }
  float v = fmaxf(acc + b2[lane], 0.f);
  float2 fw = ((const float2*)fcW)[lane];
  float f0 = wave_sum(v * fw.x);
  float f1 = wave_sum(v * fw.y);
  if (lane == 0) {
    out[(size_t)wid * 2 + 0] = f0 + fcb[0];
    out[(size_t)wid * 2 + 1] = f1 + fcb[1];
  }
}

extern "C" void kernel_launch(void* const* d_in, const int* in_sizes, int n_in,
                              void* d_out, int out_size, void* d_ws, size_t ws_size,
                              hipStream_t stream) {
  const float* x    = (const float*)d_in[0];
  const int*   ei   = (const int*)d_in[1];
  const float* W1   = (const float*)d_in[2];
  const float* a1s  = (const float*)d_in[3];
  const float* a1d  = (const float*)d_in[4];
  const float* b1   = (const float*)d_in[5];
  const float* W2   = (const float*)d_in[6];
  const float* a2s  = (const float*)d_in[7];
  const float* a2d  = (const float*)d_in[8];
  const float* b2   = (const float*)d_in[9];
  const float* fcW  = (const float*)d_in[10];
  const float* fcb  = (const float*)d_in[11];
  float* out = (float*)d_out;

  char* p = (char*)d_ws;
  float* xa    = (float*)p; p += (size_t)N_NODES * IN_C * 4;
  float* h2    = (float*)p; p += (size_t)N_NODES * OUT2 * 4;
  float* as1   = (float*)p; p += (size_t)N_NODES * 4;   // reused for layer-2 scores
  float* ad1   = (float*)p; p += (size_t)N_NODES * 4;
  float* w1s   = (float*)p; p += 256 * 4;
  float* w1d   = (float*)p; p += 256 * 4;
  int* row_ptr = (int*)p;   p += (size_t)(N_NODES + 4) * 4;
  int* deg     = (int*)p;   p += (size_t)N_NODES * 4;   // also reused as cursor
  int* bsum    = (int*)p;   p += 64 * 4;
  int* boff    = (int*)p;   p += 64 * 4;
  int* csr_src = (int*)p;   p += (size_t)E_TOT * 4;
  unsigned short* W1F = (unsigned short*)p; p += (size_t)128 * 2 * 64 * 8 * 2;  // 256KB
  unsigned short* W2F = (unsigned short*)p; p += (size_t)64 * 2 * 64 * 8 * 2;   // 128KB

  const int edge_blocks = (E_TOT + 255) / 256;
  const int node_wave_blocks = (N_NODES + 3) / 4;   // 4 waves per 256-thread block
  const int m_tiles = (N_NODES + 63) / 64;
  const int scan_blocks = (N_NODES + 1023) / 1024;  // 49

  // ---- CSR build + weight prep ----
  hipMemsetAsync(deg, 0, (size_t)N_NODES * 4, stream);
  count_deg<<<edge_blocks, 256, 0, stream>>>(ei, deg);
  scanA<<<scan_blocks, 1024, 0, stream>>>(deg, bsum);
  scanB<<<1, 64, 0, stream>>>(bsum, boff, scan_blocks);
  scanC<<<scan_blocks, 1024, 0, stream>>>(deg, boff, row_ptr);
  hipMemsetAsync(deg, 0, (size_t)N_NODES * 4, stream);
  fill_csr<<<edge_blocks, 256, 0, stream>>>(ei, row_ptr, deg, csr_src);
  prep_w1_frag<<<(128 * 64 + 255) / 256, 256, 0, stream>>>(W1, W1F);
  prep_w2_frag<<<(64 * 64 + 255) / 256, 256, 0, stream>>>(W2, W2F);

  // ---- layer 1: scores -> fused softmax+aggregate (input space) ----
  matvec_w1<<<(IN_C + 3) / 4, 256, 0, stream>>>(W1, a1s, a1d, w1s, w1d);
  node_scores128<<<node_wave_blocks, 256, 0, stream>>>(x, w1s, w1d, as1, ad1);
  sm_agg1<<<node_wave_blocks, 256, 0, stream>>>(row_ptr, csr_src, as1, ad1, x, xa);

  // ---- fused gemm1+relu+gemm2+layer-2 scores (bf16-split MFMA) ----
  fused_gemm_mfma<<<m_tiles, 256, 0, stream>>>(xa, W1F, b1, W2F,
                                               a2s, a2d, h2, as1, ad1);

  // ---- layer 2: fused softmax+aggregate+relu+head ----
  sm_agg2_final<<<node_wave_blocks, 256, 0, stream>>>(row_ptr, csr_src, as1, ad1, h2, b2,
                                                      fcW, fcb, out);
}

// Round 8
// 272.876 us; speedup vs baseline: 1.5479x; 1.1298x over previous
//
#include <hip/hip_runtime.h>

#define N_NODES 50000
#define N_EDGES 400000
#define E_TOT   (N_EDGES + N_NODES)   // 450000, self-loops appended
#define IN_C 128
#define HID  512
#define OUT2 64
#define NEG_SLOPE 0.2f

typedef short bf16x8 __attribute__((ext_vector_type(8)));
typedef float f32x4  __attribute__((ext_vector_type(4)));

__device__ __forceinline__ float wave_sum(float v) {
#pragma unroll
  for (int o = 32; o > 0; o >>= 1) v += __shfl_xor(v, o, 64);
  return v;
}
__device__ __forceinline__ int wave_sum_i(int v) {
#pragma unroll
  for (int o = 32; o > 0; o >>= 1) v += __shfl_xor(v, o, 64);
  return v;
}
__device__ __forceinline__ float wave_max(float v) {
#pragma unroll
  for (int o = 32; o > 0; o >>= 1) v = fmaxf(v, __shfl_xor(v, o, 64));
  return v;
}
__device__ __forceinline__ float leaky(float t) {
  return (t > 0.f) ? t : NEG_SLOPE * t;
}

// fp32 -> bf16 (RNE) and hi/lo split: x ~= hi + lo, |err| <= 2^-18 |x|
__device__ __forceinline__ unsigned short bf16_rne(float x) {
  unsigned u = __float_as_uint(x);
  u += 0x7fffu + ((u >> 16) & 1u);
  return (unsigned short)(u >> 16);
}
__device__ __forceinline__ void split_bf16(float x, unsigned short& h, unsigned short& l) {
  h = bf16_rne(x);
  float hf = __uint_as_float(((unsigned)h) << 16);
  l = bf16_rne(x - hf);
}

// src/dst of logical edge e (e >= N_EDGES are self-loops)
__device__ __forceinline__ int esrc(const int* __restrict__ ei, int e) {
  return (e < N_EDGES) ? ei[e] : (e - N_EDGES);
}
__device__ __forceinline__ int edst(const int* __restrict__ ei, int e) {
  return (e < N_EDGES) ? ei[N_EDGES + e] : (e - N_EDGES);
}

// ---- CSR build -------------------------------------------------------------
__global__ void count_deg(const int* __restrict__ ei, int* __restrict__ deg) {
  int e = blockIdx.x * blockDim.x + threadIdx.x;
  if (e >= E_TOT) return;
  atomicAdd(&deg[edst(ei, e)], 1);
}

__global__ void scanA(const int* __restrict__ deg, int* __restrict__ bsum) {
  __shared__ int ws[16];
  int t = threadIdx.x, lane = t & 63, w = t >> 6;
  int i = blockIdx.x * 1024 + t;
  int v = (i < N_NODES) ? deg[i] : 0;
  int s = wave_sum_i(v);
  if (lane == 0) ws[w] = s;
  __syncthreads();
  if (t == 0) {
    int tot = 0;
#pragma unroll
    for (int k = 0; k < 16; k++) tot += ws[k];
    bsum[blockIdx.x] = tot;
  }
}

__global__ void scanB(const int* __restrict__ bsum, int* __restrict__ boff, int nb) {
  int lane = threadIdx.x;  // 64 threads
  int v = (lane < nb) ? bsum[lane] : 0;
  int sc = v;
#pragma unroll
  for (int off = 1; off < 64; off <<= 1) {
    int u = __shfl_up(sc, off, 64);
    if (lane >= off) sc += u;
  }
  if (lane < nb) boff[lane] = sc - v;  // exclusive
}

__global__ void scanC(const int* __restrict__ deg, const int* __restrict__ boff,
                      int* __restrict__ row_ptr) {
  __shared__ int ws[16];
  int t = threadIdx.x, lane = t & 63, w = t >> 6;
  int i = blockIdx.x * 1024 + t;
  int v = (i < N_NODES) ? deg[i] : 0;
  int sc = v;
#pragma unroll
  for (int off = 1; off < 64; off <<= 1) {
    int u = __shfl_up(sc, off, 64);
    if (lane >= off) sc += u;
  }
  if (lane == 63) ws[w] = sc;
  __syncthreads();
  if (w == 0 && lane < 16) {
    int u = ws[lane];
#pragma unroll
    for (int off = 1; off < 16; off <<= 1) {
      int uu = __shfl_up(u, off, 64);
      if (lane >= off) u += uu;
    }
    ws[lane] = u;
  }
  __syncthreads();
  int excl = ((w > 0) ? ws[w - 1] : 0) + boff[blockIdx.x];
  if (i < N_NODES) row_ptr[i + 1] = sc + excl;
  if (blockIdx.x == 0 && t == 0) row_ptr[0] = 0;
}

__global__ void fill_csr(const int* __restrict__ ei, const int* __restrict__ row_ptr,
                         int* __restrict__ cursor, int* __restrict__ csr_src) {
  int e = blockIdx.x * blockDim.x + threadIdx.x;
  if (e >= E_TOT) return;
  int d = edst(ei, e);
  int pos = atomicAdd(&cursor[d], 1);
  csr_src[row_ptr[d] + pos] = esrc(ei, e);
}

// ---- weight prep: MFMA-fragment-ordered hi/lo bf16 -------------------------
// W1F layout: frag fi = ((jt*4+n)*4+ks), lane l:
//   col = jt*64+n*16+(l&15), k = ks*32+(l>>4)*8 .. +8
__global__ void prep_w1_frag(const float* __restrict__ W1, unsigned short* __restrict__ W1F) {
  int t = blockIdx.x * 256 + threadIdx.x;   // 8192 lane-tasks
  if (t >= 128 * 64) return;
  int fi = t >> 6, l = t & 63;
  int ks = fi & 3, n = (fi >> 2) & 3, jt = fi >> 4;
  int col = jt * 64 + n * 16 + (l & 15);
  int k0 = ks * 32 + (l >> 4) * 8;
  unsigned short hv[8], lv[8];
#pragma unroll
  for (int e = 0; e < 8; e++)
    split_bf16(W1[(size_t)(k0 + e) * HID + col], hv[e], lv[e]);
  unsigned short* ph = W1F + ((size_t)(fi * 2 + 0) * 64 + l) * 8;
  unsigned short* pl = W1F + ((size_t)(fi * 2 + 1) * 64 + l) * 8;
#pragma unroll
  for (int e = 0; e < 8; e++) { ph[e] = hv[e]; pl[e] = lv[e]; }
}

// W2F layout: frag fi2 = ((jt*2+ks)*4+n), lane l:
//   col = n*16+(l&15), k2 = jt*64+ks*32+(l>>4)*8 .. +8
__global__ void prep_w2_frag(const float* __restrict__ W2, unsigned short* __restrict__ W2F) {
  int t = blockIdx.x * 256 + threadIdx.x;   // 4096 lane-tasks
  if (t >= 64 * 64) return;
  int fi = t >> 6, l = t & 63;
  int n = fi & 3, ks = (fi >> 2) & 1, jt = fi >> 3;
  int col = n * 16 + (l & 15);
  int k0 = jt * 64 + ks * 32 + (l >> 4) * 8;
  unsigned short hv[8], lv[8];
#pragma unroll
  for (int e = 0; e < 8; e++)
    split_bf16(W2[(size_t)(k0 + e) * OUT2 + col], hv[e], lv[e]);
  unsigned short* ph = W2F + ((size_t)(fi * 2 + 0) * 64 + l) * 8;
  unsigned short* pl = W2F + ((size_t)(fi * 2 + 1) * 64 + l) * 8;
#pragma unroll
  for (int e = 0; e < 8; e++) { ph[e] = hv[e]; pl[e] = lv[e]; }
}

// ---- layer-1 score vectors: w1s = W1 @ a1_src, w1d = W1 @ a1_dst ----------
__global__ void matvec_w1(const float* __restrict__ W1, const float* __restrict__ a1s,
                          const float* __restrict__ a1d, float* __restrict__ w1s,
                          float* __restrict__ w1d) {
  int wid = (blockIdx.x * blockDim.x + threadIdx.x) >> 6;
  int lane = threadIdx.x & 63;
  if (wid >= IN_C) return;
  const float* row = W1 + (size_t)wid * HID;
  float s = 0.f, d = 0.f;
#pragma unroll
  for (int j0 = 0; j0 < HID; j0 += 64) {
    float w = row[j0 + lane];
    s += w * a1s[j0 + lane];
    d += w * a1d[j0 + lane];
  }
  s = wave_sum(s); d = wave_sum(d);
  if (lane == 0) { w1s[wid] = s; w1d[wid] = d; }
}

// alpha_s[i] = x[i].w1s ; alpha_d[i] = x[i].w1d  (one wave per node, float2)
__global__ void node_scores128(const float* __restrict__ x, const float* __restrict__ ws,
                               const float* __restrict__ wd, float* __restrict__ as_,
                               float* __restrict__ ad_) {
  int wid = (blockIdx.x * blockDim.x + threadIdx.x) >> 6;
  int lane = threadIdx.x & 63;
  if (wid >= N_NODES) return;
  float2 v = ((const float2*)(x + (size_t)wid * IN_C))[lane];
  float2 w1 = ((const float2*)ws)[lane];
  float2 w2 = ((const float2*)wd)[lane];
  float s = wave_sum(v.x * w1.x + v.y * w1.y);
  float d = wave_sum(v.x * w2.x + v.y * w2.y);
  if (lane == 0) { as_[wid] = s; ad_[wid] = d; }
}

// ---- fused segment-softmax + aggregation, layer 1 (128 ch, input space) ----
// gather loop 4x-unrolled: 4 independent row loads in flight per iteration
__global__ void sm_agg1(const int* __restrict__ row_ptr, const int* __restrict__ csr_src,
                        const float* __restrict__ as_, const float* __restrict__ ad_,
                        const float* __restrict__ x, float* __restrict__ xa) {
  int wid = (blockIdx.x * blockDim.x + threadIdx.x) >> 6;
  int lane = threadIdx.x & 63;
  if (wid >= N_NODES) return;
  int beg = row_ptr[wid], end = row_ptr[wid + 1];
  int deg = end - beg;
  float adv = ad_[wid];
  const float2* x2 = (const float2*)x;
  float2 acc = make_float2(0.f, 0.f);
  if (deg <= 64) {
    int s = 0; float sc = -3.4e38f;
    if (lane < deg) { s = csr_src[beg + lane]; sc = leaky(as_[s] + adv); }
    float m = wave_max(sc);
    float ex = (lane < deg) ? __expf(sc - m) : 0.f;
    float sum = wave_sum(ex);
    float a = ex / sum;
    int kk = 0;
    for (; kk + 4 <= deg; kk += 4) {
      float w0 = __shfl(a, kk, 64),     w1 = __shfl(a, kk + 1, 64);
      float w2 = __shfl(a, kk + 2, 64), w3 = __shfl(a, kk + 3, 64);
      int s0 = __shfl(s, kk, 64),     s1 = __shfl(s, kk + 1, 64);
      int s2 = __shfl(s, kk + 2, 64), s3 = __shfl(s, kk + 3, 64);
      float2 r0 = x2[(size_t)s0 * 64 + lane];
      float2 r1 = x2[(size_t)s1 * 64 + lane];
      float2 r2 = x2[(size_t)s2 * 64 + lane];
      float2 r3 = x2[(size_t)s3 * 64 + lane];
      acc.x += w0 * r0.x + w1 * r1.x + w2 * r2.x + w3 * r3.x;
      acc.y += w0 * r0.y + w1 * r1.y + w2 * r2.y + w3 * r3.y;
    }
    for (; kk < deg; kk++) {
      float w = __shfl(a, kk, 64);
      int sv = __shfl(s, kk, 64);
      float2 r = x2[(size_t)sv * 64 + lane];
      acc.x += w * r.x; acc.y += w * r.y;
    }
  } else {  // fallback (kept for correctness on any graph)
    float m = -3.4e38f;
    for (int k = beg + lane; k < end; k += 64)
      m = fmaxf(m, leaky(as_[csr_src[k]] + adv));
    m = wave_max(m);
    float sum = 0.f;
    for (int k = beg + lane; k < end; k += 64)
      sum += __expf(leaky(as_[csr_src[k]] + adv) - m);
    sum = wave_sum(sum);
    float inv = 1.f / sum;
    for (int k = beg; k < end; k++) {
      int sv = csr_src[k];
      float w = __expf(leaky(as_[sv] + adv) - m) * inv;
      float2 r = x2[(size_t)sv * 64 + lane];
      acc.x += w * r.x; acc.y += w * r.y;
    }
  }
  ((float2*)(xa + (size_t)wid * IN_C))[lane] = acc;
}

// ---- fused gemm1(relu) + gemm2 + layer-2 node scores, bf16-split MFMA ------
// Barrier-free: each wave owns a 32-row M-stripe end-to-end. A fragments
// loaded global->register (no LDS); TS slab stripes are wave-private.
__launch_bounds__(128, 2)
__global__ void fused_gemm_mfma(const float* __restrict__ xa,
                                const unsigned short* __restrict__ W1F,
                                const float* __restrict__ b1,
                                const unsigned short* __restrict__ W2F,
                                const float* __restrict__ a2s, const float* __restrict__ a2d,
                                float* __restrict__ h2, float* __restrict__ as2,
                                float* __restrict__ ad2) {
  __shared__ unsigned int TS[64][64];   // 16KB; wave w owns rows w*32..w*32+31
  int t = threadIdx.x;
  int w = t >> 6;        // wave id (0..1)
  int l = t & 63;
  int lr = l & 15;       // row/col within 16-tile
  int G  = l >> 4;       // k-group
  int base = blockIdx.x * 64 + w * 32;  // first node row of this wave

  // ---- prologue: A fragments global -> registers, fp32 -> hi/lo bf16 ----
  bf16x8 aFh[2][4], aFl[2][4];
#pragma unroll
  for (int m = 0; m < 2; m++) {
    int grow = base + m * 16 + lr;
    bool ok = (grow < N_NODES);
    const float* rp = xa + (size_t)grow * IN_C;
#pragma unroll
    for (int ks = 0; ks < 4; ks++) {
      float4 v0 = make_float4(0.f, 0.f, 0.f, 0.f), v1 = v0;
      if (ok) {
        v0 = *(const float4*)(rp + ks * 32 + G * 8);
        v1 = *(const float4*)(rp + ks * 32 + G * 8 + 4);
      }
      unsigned short h, lo;
      split_bf16(v0.x, h, lo); aFh[m][ks][0] = (short)h; aFl[m][ks][0] = (short)lo;
      split_bf16(v0.y, h, lo); aFh[m][ks][1] = (short)h; aFl[m][ks][1] = (short)lo;
      split_bf16(v0.z, h, lo); aFh[m][ks][2] = (short)h; aFl[m][ks][2] = (short)lo;
      split_bf16(v0.w, h, lo); aFh[m][ks][3] = (short)h; aFl[m][ks][3] = (short)lo;
      split_bf16(v1.x, h, lo); aFh[m][ks][4] = (short)h; aFl[m][ks][4] = (short)lo;
      split_bf16(v1.y, h, lo); aFh[m][ks][5] = (short)h; aFl[m][ks][5] = (short)lo;
      split_bf16(v1.z, h, lo); aFh[m][ks][6] = (short)h; aFl[m][ks][6] = (short)lo;
      split_bf16(v1.w, h, lo); aFh[m][ks][7] = (short)h; aFl[m][ks][7] = (short)lo;
    }
  }

  const bf16x8* W1Fv = (const bf16x8*)W1F;
  const bf16x8* W2Fv = (const bf16x8*)W2F;

  f32x4 acc2[2][4];
#pragma unroll
  for (int m = 0; m < 2; m++)
#pragma unroll
    for (int n = 0; n < 4; n++) acc2[m][n] = (f32x4){0.f, 0.f, 0.f, 0.f};

  for (int jt = 0; jt < 8; jt++) {
    // --- gemm1 slab: cols jt*64 + n*16 + lr, K = 128 ---
    f32x4 acc1[2][4];
#pragma unroll
    for (int m = 0; m < 2; m++)
#pragma unroll
      for (int n = 0; n < 4; n++) acc1[m][n] = (f32x4){0.f, 0.f, 0.f, 0.f};
#pragma unroll
    for (int ks = 0; ks < 4; ks++) {
#pragma unroll
      for (int n = 0; n < 4; n++) {
        int fi = (jt * 4 + n) * 4 + ks;
        bf16x8 b_h = W1Fv[(size_t)(fi * 2 + 0) * 64 + l];
        bf16x8 b_l = W1Fv[(size_t)(fi * 2 + 1) * 64 + l];
#pragma unroll
        for (int m = 0; m < 2; m++) {
          acc1[m][n] = __builtin_amdgcn_mfma_f32_16x16x32_bf16(aFh[m][ks], b_h, acc1[m][n], 0, 0, 0);
          acc1[m][n] = __builtin_amdgcn_mfma_f32_16x16x32_bf16(aFl[m][ks], b_h, acc1[m][n], 0, 0, 0);
          acc1[m][n] = __builtin_amdgcn_mfma_f32_16x16x32_bf16(aFh[m][ks], b_l, acc1[m][n], 0, 0, 0);
        }
      }
    }
    // --- epilogue: bias + relu, split, write TS (own stripe; no barrier) ---
#pragma unroll
    for (int n = 0; n < 4; n++) {
      float bv = b1[jt * 64 + n * 16 + lr];
#pragma unroll
      for (int m = 0; m < 2; m++) {
#pragma unroll
        for (int r = 0; r < 4; r++) {
          float vv = fmaxf(acc1[m][n][r] + bv, 0.f);
          unsigned short hh, ll;
          split_bf16(vv, hh, ll);
          int rowL = w * 32 + m * 16 + G * 4 + r;
          int colS = (n * 16 + lr) ^ ((rowL & 7) << 2);
          TS[rowL][colS] = (unsigned)hh | ((unsigned)ll << 16);
        }
      }
    }
    // --- gemm2 partial: acc2 += out1_slab @ W2[jt*64 .. +63, :] ---
#pragma unroll
    for (int ks = 0; ks < 2; ks++) {
      int kl = ks * 32 + G * 8;
      bf16x8 a2h[2], a2l[2];
#pragma unroll
      for (int m = 0; m < 2; m++) {
        int rowA = w * 32 + m * 16 + lr;
        int sw2 = (rowA & 7) << 2;
        uint4 q0 = *(const uint4*)&TS[rowA][(kl + 0) ^ sw2];
        uint4 q1 = *(const uint4*)&TS[rowA][(kl + 4) ^ sw2];
        a2h[m][0] = (short)(q0.x & 0xffff); a2l[m][0] = (short)(q0.x >> 16);
        a2h[m][1] = (short)(q0.y & 0xffff); a2l[m][1] = (short)(q0.y >> 16);
        a2h[m][2] = (short)(q0.z & 0xffff); a2l[m][2] = (short)(q0.z >> 16);
        a2h[m][3] = (short)(q0.w & 0xffff); a2l[m][3] = (short)(q0.w >> 16);
        a2h[m][4] = (short)(q1.x & 0xffff); a2l[m][4] = (short)(q1.x >> 16);
        a2h[m][5] = (short)(q1.y & 0xffff); a2l[m][5] = (short)(q1.y >> 16);
        a2h[m][6] = (short)(q1.z & 0xffff); a2l[m][6] = (short)(q1.z >> 16);
        a2h[m][7] = (short)(q1.w & 0xffff); a2l[m][7] = (short)(q1.w >> 16);
      }
#pragma unroll
      for (int n = 0; n < 4; n++) {
        int fi2 = (jt * 2 + ks) * 4 + n;
        bf16x8 b_h = W2Fv[(size_t)(fi2 * 2 + 0) * 64 + l];
        bf16x8 b_l = W2Fv[(size_t)(fi2 * 2 + 1) * 64 + l];
#pragma unroll
        for (int m = 0; m < 2; m++) {
          acc2[m][n] = __builtin_amdgcn_mfma_f32_16x16x32_bf16(a2h[m], b_h, acc2[m][n], 0, 0, 0);
          acc2[m][n] = __builtin_amdgcn_mfma_f32_16x16x32_bf16(a2l[m], b_h, acc2[m][n], 0, 0, 0);
          acc2[m][n] = __builtin_amdgcn_mfma_f32_16x16x32_bf16(a2h[m], b_l, acc2[m][n], 0, 0, 0);
        }
      }
    }
  }

  // ---- epilogue: h2 write + fused layer-2 node scores ----
#pragma unroll
  for (int m = 0; m < 2; m++) {
#pragma unroll
    for (int r = 0; r < 4; r++) {
      int grow = base + m * 16 + G * 4 + r;
      if (grow < N_NODES) {
#pragma unroll
        for (int n = 0; n < 4; n++)
          h2[(size_t)grow * OUT2 + n * 16 + lr] = acc2[m][n][r];
      }
      float sp = 0.f, dp = 0.f;
#pragma unroll
      for (int n = 0; n < 4; n++) {
        float v = acc2[m][n][r];
        sp += v * a2s[n * 16 + lr];
        dp += v * a2d[n * 16 + lr];
      }
#pragma unroll
      for (int o = 1; o < 16; o <<= 1) {
        sp += __shfl_xor(sp, o, 64);
        dp += __shfl_xor(dp, o, 64);
      }
      if (lr == 0 && grow < N_NODES) { as2[grow] = sp; ad2[grow] = dp; }
    }
  }
}

// ---- fused layer-2 softmax + aggregation + relu + FC head ------------------
__global__ void sm_agg2_final(const int* __restrict__ row_ptr, const int* __restrict__ csr_src,
                              const float* __restrict__ as_, const float* __restrict__ ad_,
                              const float* __restrict__ h2, const float* __restrict__ b2,
                              const float* __restrict__ fcW, const float* __restrict__ fcb,
                              float* __restrict__ out) {
  int wid = (blockIdx.x * blockDim.x + threadIdx.x) >> 6;
  int lane = threadIdx.x & 63;
  if (wid >= N_NODES) return;
  int beg = row_ptr[wid], end = row_ptr[wid + 1];
  int deg = end - beg;
  float adv = ad_[wid];
  float acc = 0.f;
  if (deg <= 64) {
    int s = 0; float sc = -3.4e38f;
    if (lane < deg) { s = csr_src[beg + lane]; sc = leaky(as_[s] + adv); }
    float m = wave_max(sc);
    float ex = (lane < deg) ? __expf(sc - m) : 0.f;
    float sum = wave_sum(ex);
    float a = ex / sum;
    int kk = 0;
    for (; kk + 4 <= deg; kk += 4) {
      float w0 = __shfl(a, kk, 64),     w1 = __shfl(a, kk + 1, 64);
      float w2 = __shfl(a, kk + 2, 64), w3 = __shfl(a, kk + 3, 64);
      int s0 = __shfl(s, kk, 64),     s1 = __shfl(s, kk + 1, 64);
      int s2 = __shfl(s, kk + 2, 64), s3 = __shfl(s, kk + 3, 64);
      float r0 = h2[(size_t)s0 * OUT2 + lane];
      float r1 = h2[(size_t)s1 * OUT2 + lane];
      float r2 = h2[(size_t)s2 * OUT2 + lane];
      float r3 = h2[(size_t)s3 * OUT2 + lane];
      acc += w0 * r0 + w1 * r1 + w2 * r2 + w3 * r3;
    }
    for (; kk < deg; kk++) {
      float w = __shfl(a, kk, 64);
      int sv = __shfl(s, kk, 64);
      acc += w * h2[(size_t)sv * OUT2 + lane];
    }
  } else {
    float m = -3.4e38f;
    for (int k = beg + lane; k < end; k += 64)
      m = fmaxf(m, leaky(as_[csr_src[k]] + adv));
    m = wave_max(m);
    float sum = 0.f;
    for (int k = beg + lane; k < end; k += 64)
      sum += __expf(leaky(as_[csr_src[k]] + adv) - m);
    sum = wave_sum(sum);
    float inv = 1.f / sum;
    for (int k = beg; k < end; k++) {
      int sv = csr_src[k];
      float w = __expf(leaky(as_[sv] + adv) - m) * inv;
      acc += w * h2[(size_t)sv * OUT2 + lane];
    }
  }
  float v = fmaxf(acc + b2[lane], 0.f);
  float2 fw = ((const float2*)fcW)[lane];
  float f0 = wave_sum(v * fw.x);
  float f1 = wave_sum(v * fw.y);
  if (lane == 0) {
    out[(size_t)wid * 2 + 0] = f0 + fcb[0];
    out[(size_t)wid * 2 + 1] = f1 + fcb[1];
  }
}

extern "C" void kernel_launch(void* const* d_in, const int* in_sizes, int n_in,
                              void* d_out, int out_size, void* d_ws, size_t ws_size,
                              hipStream_t stream) {
  const float* x    = (const float*)d_in[0];
  const int*   ei   = (const int*)d_in[1];
  const float* W1   = (const float*)d_in[2];
  const float* a1s  = (const float*)d_in[3];
  const float* a1d  = (const float*)d_in[4];
  const float* b1   = (const float*)d_in[5];
  const float* W2   = (const float*)d_in[6];
  const float* a2s  = (const float*)d_in[7];
  const float* a2d  = (const float*)d_in[8];
  const float* b2   = (const float*)d_in[9];
  const float* fcW  = (const float*)d_in[10];
  const float* fcb  = (const float*)d_in[11];
  float* out = (float*)d_out;

  char* p = (char*)d_ws;
  float* xa    = (float*)p; p += (size_t)N_NODES * IN_C * 4;
  float* h2    = (float*)p; p += (size_t)N_NODES * OUT2 * 4;
  float* as1   = (float*)p; p += (size_t)N_NODES * 4;   // reused for layer-2 scores
  float* ad1   = (float*)p; p += (size_t)N_NODES * 4;
  float* w1s   = (float*)p; p += 256 * 4;
  float* w1d   = (float*)p; p += 256 * 4;
  int* row_ptr = (int*)p;   p += (size_t)(N_NODES + 4) * 4;
  int* deg     = (int*)p;   p += (size_t)N_NODES * 4;   // also reused as cursor
  int* bsum    = (int*)p;   p += 64 * 4;
  int* boff    = (int*)p;   p += 64 * 4;
  int* csr_src = (int*)p;   p += (size_t)E_TOT * 4;
  unsigned short* W1F = (unsigned short*)p; p += (size_t)128 * 2 * 64 * 8 * 2;  // 256KB
  unsigned short* W2F = (unsigned short*)p; p += (size_t)64 * 2 * 64 * 8 * 2;   // 128KB

  const int edge_blocks = (E_TOT + 255) / 256;
  const int node_wave_blocks = (N_NODES + 3) / 4;   // 4 waves per 256-thread block
  const int m_tiles64 = (N_NODES + 63) / 64;        // 782 blocks of 128 threads
  const int scan_blocks = (N_NODES + 1023) / 1024;  // 49

  // ---- CSR build + weight prep ----
  hipMemsetAsync(deg, 0, (size_t)N_NODES * 4, stream);
  count_deg<<<edge_blocks, 256, 0, stream>>>(ei, deg);
  scanA<<<scan_blocks, 1024, 0, stream>>>(deg, bsum);
  scanB<<<1, 64, 0, stream>>>(bsum, boff, scan_blocks);
  scanC<<<scan_blocks, 1024, 0, stream>>>(deg, boff, row_ptr);
  hipMemsetAsync(deg, 0, (size_t)N_NODES * 4, stream);
  fill_csr<<<edge_blocks, 256, 0, stream>>>(ei, row_ptr, deg, csr_src);
  prep_w1_frag<<<(128 * 64 + 255) / 256, 256, 0, stream>>>(W1, W1F);
  prep_w2_frag<<<(64 * 64 + 255) / 256, 256, 0, stream>>>(W2, W2F);

  // ---- layer 1: scores -> fused softmax+aggregate (input space) ----
  matvec_w1<<<(IN_C + 3) / 4, 256, 0, stream>>>(W1, a1s, a1d, w1s, w1d);
  node_scores128<<<node_wave_blocks, 256, 0, stream>>>(x, w1s, w1d, as1, ad1);
  sm_agg1<<<node_wave_blocks, 256, 0, stream>>>(row_ptr, csr_src, as1, ad1, x, xa);

  // ---- fused gemm1+relu+gemm2+layer-2 scores (bf16-split MFMA, barrier-free) ----
  fused_gemm_mfma<<<m_tiles64, 128, 0, stream>>>(xa, W1F, b1, W2F,
                                                 a2s, a2d, h2, as1, ad1);

  // ---- layer 2: fused softmax+aggregate+relu+head ----
  sm_agg2_final<<<node_wave_blocks, 256, 0, stream>>>(row_ptr, csr_src, as1, ad1, h2, b2,
                                                      fcW, fcb, out);
}

// Round 10
// 266.883 us; speedup vs baseline: 1.5826x; 1.0225x over previous
//
#include <hip/hip_runtime.h>

#define N_NODES 50000
#define N_EDGES 400000
#define E_TOT   (N_EDGES + N_NODES)   // 450000, self-loops appended
#define IN_C 128
#define HID  512
#define OUT2 64
#define NEG_SLOPE 0.2f

typedef short bf16x8 __attribute__((ext_vector_type(8)));
typedef float f32x4  __attribute__((ext_vector_type(4)));

__device__ __forceinline__ float wave_sum(float v) {
#pragma unroll
  for (int o = 32; o > 0; o >>= 1) v += __shfl_xor(v, o, 64);
  return v;
}
__device__ __forceinline__ int wave_sum_i(int v) {
#pragma unroll
  for (int o = 32; o > 0; o >>= 1) v += __shfl_xor(v, o, 64);
  return v;
}
__device__ __forceinline__ float wave_max(float v) {
#pragma unroll
  for (int o = 32; o > 0; o >>= 1) v = fmaxf(v, __shfl_xor(v, o, 64));
  return v;
}
__device__ __forceinline__ float leaky(float t) {
  return (t > 0.f) ? t : NEG_SLOPE * t;
}

// fp32 -> bf16 (RNE) and hi/lo split: x ~= hi + lo, |err| <= 2^-18 |x|
__device__ __forceinline__ unsigned short bf16_rne(float x) {
  unsigned u = __float_as_uint(x);
  u += 0x7fffu + ((u >> 16) & 1u);
  return (unsigned short)(u >> 16);
}
__device__ __forceinline__ void split_bf16(float x, unsigned short& h, unsigned short& l) {
  h = bf16_rne(x);
  float hf = __uint_as_float(((unsigned)h) << 16);
  l = bf16_rne(x - hf);
}

// src/dst of logical edge e (e >= N_EDGES are self-loops)
__device__ __forceinline__ int esrc(const int* __restrict__ ei, int e) {
  return (e < N_EDGES) ? ei[e] : (e - N_EDGES);
}
__device__ __forceinline__ int edst(const int* __restrict__ ei, int e) {
  return (e < N_EDGES) ? ei[N_EDGES + e] : (e - N_EDGES);
}

// ---- CSR build -------------------------------------------------------------
__global__ void count_deg(const int* __restrict__ ei, int* __restrict__ deg) {
  int e = blockIdx.x * blockDim.x + threadIdx.x;
  if (e >= E_TOT) return;
  atomicAdd(&deg[edst(ei, e)], 1);
}

__global__ void scanA(const int* __restrict__ deg, int* __restrict__ bsum) {
  __shared__ int ws[16];
  int t = threadIdx.x, lane = t & 63, w = t >> 6;
  int i = blockIdx.x * 1024 + t;
  int v = (i < N_NODES) ? deg[i] : 0;
  int s = wave_sum_i(v);
  if (lane == 0) ws[w] = s;
  __syncthreads();
  if (t == 0) {
    int tot = 0;
#pragma unroll
    for (int k = 0; k < 16; k++) tot += ws[k];
    bsum[blockIdx.x] = tot;
  }
}

__global__ void scanB(const int* __restrict__ bsum, int* __restrict__ boff, int nb) {
  int lane = threadIdx.x;  // 64 threads
  int v = (lane < nb) ? bsum[lane] : 0;
  int sc = v;
#pragma unroll
  for (int off = 1; off < 64; off <<= 1) {
    int u = __shfl_up(sc, off, 64);
    if (lane >= off) sc += u;
  }
  if (lane < nb) boff[lane] = sc - v;  // exclusive
}

__global__ void scanC(const int* __restrict__ deg, const int* __restrict__ boff,
                      int* __restrict__ row_ptr) {
  __shared__ int ws[16];
  int t = threadIdx.x, lane = t & 63, w = t >> 6;
  int i = blockIdx.x * 1024 + t;
  int v = (i < N_NODES) ? deg[i] : 0;
  int sc = v;
#pragma unroll
  for (int off = 1; off < 64; off <<= 1) {
    int u = __shfl_up(sc, off, 64);
    if (lane >= off) sc += u;
  }
  if (lane == 63) ws[w] = sc;
  __syncthreads();
  if (w == 0 && lane < 16) {
    int u = ws[lane];
#pragma unroll
    for (int off = 1; off < 16; off <<= 1) {
      int uu = __shfl_up(u, off, 64);
      if (lane >= off) u += uu;
    }
    ws[lane] = u;
  }
  __syncthreads();
  int excl = ((w > 0) ? ws[w - 1] : 0) + boff[blockIdx.x];
  if (i < N_NODES) row_ptr[i + 1] = sc + excl;
  if (blockIdx.x == 0 && t == 0) row_ptr[0] = 0;
}

__global__ void fill_csr(const int* __restrict__ ei, const int* __restrict__ row_ptr,
                         int* __restrict__ cursor, int* __restrict__ csr_src) {
  int e = blockIdx.x * blockDim.x + threadIdx.x;
  if (e >= E_TOT) return;
  int d = edst(ei, e);
  int pos = atomicAdd(&cursor[d], 1);
  csr_src[row_ptr[d] + pos] = esrc(ei, e);
}

// ---- merged weight prep: W1F frags + W2F frags + matvec_w1 -----------------
// blocks [0,32): W1 frags; [32,48): W2 frags; [48,80): w1s/w1d matvec
__global__ void prep_weights(const float* __restrict__ W1, const float* __restrict__ W2,
                             const float* __restrict__ a1s, const float* __restrict__ a1d,
                             unsigned short* __restrict__ W1F, unsigned short* __restrict__ W2F,
                             float* __restrict__ w1s, float* __restrict__ w1d) {
  int b = blockIdx.x;
  if (b < 32) {
    int t = b * 256 + threadIdx.x;   // 8192 lane-tasks
    int fi = t >> 6, l = t & 63;
    int ks = fi & 3, n = (fi >> 2) & 3, jt = fi >> 4;
    int col = jt * 64 + n * 16 + (l & 15);
    int k0 = ks * 32 + (l >> 4) * 8;
    unsigned short hv[8], lv[8];
#pragma unroll
    for (int e = 0; e < 8; e++)
      split_bf16(W1[(size_t)(k0 + e) * HID + col], hv[e], lv[e]);
    unsigned short* ph = W1F + ((size_t)(fi * 2 + 0) * 64 + l) * 8;
    unsigned short* pl = W1F + ((size_t)(fi * 2 + 1) * 64 + l) * 8;
#pragma unroll
    for (int e = 0; e < 8; e++) { ph[e] = hv[e]; pl[e] = lv[e]; }
  } else if (b < 48) {
    int t = (b - 32) * 256 + threadIdx.x;   // 4096 lane-tasks
    int fi = t >> 6, l = t & 63;
    int n = fi & 3, ks = (fi >> 2) & 1, jt = fi >> 3;
    int col = n * 16 + (l & 15);
    int k0 = jt * 64 + ks * 32 + (l >> 4) * 8;
    unsigned short hv[8], lv[8];
#pragma unroll
    for (int e = 0; e < 8; e++)
      split_bf16(W2[(size_t)(k0 + e) * OUT2 + col], hv[e], lv[e]);
    unsigned short* ph = W2F + ((size_t)(fi * 2 + 0) * 64 + l) * 8;
    unsigned short* pl = W2F + ((size_t)(fi * 2 + 1) * 64 + l) * 8;
#pragma unroll
    for (int e = 0; e < 8; e++) { ph[e] = hv[e]; pl[e] = lv[e]; }
  } else {
    int wid = ((b - 48) * 256 + threadIdx.x) >> 6;
    int lane = threadIdx.x & 63;
    if (wid >= IN_C) return;
    const float* row = W1 + (size_t)wid * HID;
    float s = 0.f, d = 0.f;
#pragma unroll
    for (int j0 = 0; j0 < HID; j0 += 64) {
      float w = row[j0 + lane];
      s += w * a1s[j0 + lane];
      d += w * a1d[j0 + lane];
    }
    s = wave_sum(s); d = wave_sum(d);
    if (lane == 0) { w1s[wid] = s; w1d[wid] = d; }
  }
}

// alpha_s[i] = x[i].w1s ; alpha_d[i] = x[i].w1d  (one wave per node, float2)
__global__ void node_scores128(const float* __restrict__ x, const float* __restrict__ ws,
                               const float* __restrict__ wd, float* __restrict__ as_,
                               float* __restrict__ ad_) {
  int wid = (blockIdx.x * blockDim.x + threadIdx.x) >> 6;
  int lane = threadIdx.x & 63;
  if (wid >= N_NODES) return;
  float2 v = ((const float2*)(x + (size_t)wid * IN_C))[lane];
  float2 w1 = ((const float2*)ws)[lane];
  float2 w2 = ((const float2*)wd)[lane];
  float s = wave_sum(v.x * w1.x + v.y * w1.y);
  float d = wave_sum(v.x * w2.x + v.y * w2.y);
  if (lane == 0) { as_[wid] = s; ad_[wid] = d; }
}

// ---- fused segment-softmax + aggregation, layer 1 (128 ch, input space) ----
// gather loop 8x-unrolled: covers deg~9 in one batch of in-flight loads
__global__ void sm_agg1(const int* __restrict__ row_ptr, const int* __restrict__ csr_src,
                        const float* __restrict__ as_, const float* __restrict__ ad_,
                        const float* __restrict__ x, float* __restrict__ xa) {
  int wid = (blockIdx.x * blockDim.x + threadIdx.x) >> 6;
  int lane = threadIdx.x & 63;
  if (wid >= N_NODES) return;
  int beg = row_ptr[wid], end = row_ptr[wid + 1];
  int deg = end - beg;
  float adv = ad_[wid];
  const float2* x2 = (const float2*)x;
  float2 acc = make_float2(0.f, 0.f);
  if (deg <= 64) {
    int s = 0; float sc = -3.4e38f;
    if (lane < deg) { s = csr_src[beg + lane]; sc = leaky(as_[s] + adv); }
    float m = wave_max(sc);
    float ex = (lane < deg) ? __expf(sc - m) : 0.f;
    float sum = wave_sum(ex);
    float a = ex / sum;
    int kk = 0;
    for (; kk + 8 <= deg; kk += 8) {
      float w0 = __shfl(a, kk, 64),     w1 = __shfl(a, kk + 1, 64);
      float w2 = __shfl(a, kk + 2, 64), w3 = __shfl(a, kk + 3, 64);
      float w4 = __shfl(a, kk + 4, 64), w5 = __shfl(a, kk + 5, 64);
      float w6 = __shfl(a, kk + 6, 64), w7 = __shfl(a, kk + 7, 64);
      int s0 = __shfl(s, kk, 64),     s1 = __shfl(s, kk + 1, 64);
      int s2 = __shfl(s, kk + 2, 64), s3 = __shfl(s, kk + 3, 64);
      int s4 = __shfl(s, kk + 4, 64), s5 = __shfl(s, kk + 5, 64);
      int s6 = __shfl(s, kk + 6, 64), s7 = __shfl(s, kk + 7, 64);
      float2 r0 = x2[(size_t)s0 * 64 + lane];
      float2 r1 = x2[(size_t)s1 * 64 + lane];
      float2 r2 = x2[(size_t)s2 * 64 + lane];
      float2 r3 = x2[(size_t)s3 * 64 + lane];
      float2 r4 = x2[(size_t)s4 * 64 + lane];
      float2 r5 = x2[(size_t)s5 * 64 + lane];
      float2 r6 = x2[(size_t)s6 * 64 + lane];
      float2 r7 = x2[(size_t)s7 * 64 + lane];
      acc.x += w0 * r0.x + w1 * r1.x + w2 * r2.x + w3 * r3.x
             + w4 * r4.x + w5 * r5.x + w6 * r6.x + w7 * r7.x;
      acc.y += w0 * r0.y + w1 * r1.y + w2 * r2.y + w3 * r3.y
             + w4 * r4.y + w5 * r5.y + w6 * r6.y + w7 * r7.y;
    }
    for (; kk + 4 <= deg; kk += 4) {
      float w0 = __shfl(a, kk, 64),     w1 = __shfl(a, kk + 1, 64);
      float w2 = __shfl(a, kk + 2, 64), w3 = __shfl(a, kk + 3, 64);
      int s0 = __shfl(s, kk, 64),     s1 = __shfl(s, kk + 1, 64);
      int s2 = __shfl(s, kk + 2, 64), s3 = __shfl(s, kk + 3, 64);
      float2 r0 = x2[(size_t)s0 * 64 + lane];
      float2 r1 = x2[(size_t)s1 * 64 + lane];
      float2 r2 = x2[(size_t)s2 * 64 + lane];
      float2 r3 = x2[(size_t)s3 * 64 + lane];
      acc.x += w0 * r0.x + w1 * r1.x + w2 * r2.x + w3 * r3.x;
      acc.y += w0 * r0.y + w1 * r1.y + w2 * r2.y + w3 * r3.y;
    }
    for (; kk < deg; kk++) {
      float w = __shfl(a, kk, 64);
      int sv = __shfl(s, kk, 64);
      float2 r = x2[(size_t)sv * 64 + lane];
      acc.x += w * r.x; acc.y += w * r.y;
    }
  } else {  // fallback (kept for correctness on any graph)
    float m = -3.4e38f;
    for (int k = beg + lane; k < end; k += 64)
      m = fmaxf(m, leaky(as_[csr_src[k]] + adv));
    m = wave_max(m);
    float sum = 0.f;
    for (int k = beg + lane; k < end; k += 64)
      sum += __expf(leaky(as_[csr_src[k]] + adv) - m);
    sum = wave_sum(sum);
    float inv = 1.f / sum;
    for (int k = beg; k < end; k++) {
      int sv = csr_src[k];
      float w = __expf(leaky(as_[sv] + adv) - m) * inv;
      float2 r = x2[(size_t)sv * 64 + lane];
      acc.x += w * r.x; acc.y += w * r.y;
    }
  }
  ((float2*)(xa + (size_t)wid * IN_C))[lane] = acc;
}

// ---- fused gemm1(relu) + gemm2 + layer-2 node scores, bf16-split MFMA ------
// Barrier-free; per-jt: W2 fragments prefetched up-front, gemm1 B loads
// batched per-ks (8 in flight) -> breaks the serial load->use chain.
__launch_bounds__(128, 2)
__global__ void fused_gemm_mfma(const float* __restrict__ xa,
                                const unsigned short* __restrict__ W1F,
                                const float* __restrict__ b1,
                                const unsigned short* __restrict__ W2F,
                                const float* __restrict__ a2s, const float* __restrict__ a2d,
                                float* __restrict__ h2, float* __restrict__ as2,
                                float* __restrict__ ad2) {
  __shared__ unsigned int TS[64][64];   // 16KB; wave w owns rows w*32..w*32+31
  int t = threadIdx.x;
  int w = t >> 6;        // wave id (0..1)
  int l = t & 63;
  int lr = l & 15;       // row/col within 16-tile
  int G  = l >> 4;       // k-group
  int base = blockIdx.x * 64 + w * 32;  // first node row of this wave

  // ---- prologue: A fragments global -> registers, fp32 -> hi/lo bf16 ----
  bf16x8 aFh[2][4], aFl[2][4];
#pragma unroll
  for (int m = 0; m < 2; m++) {
    int grow = base + m * 16 + lr;
    bool ok = (grow < N_NODES);
    const float* rp = xa + (size_t)grow * IN_C;
#pragma unroll
    for (int ks = 0; ks < 4; ks++) {
      float4 v0 = make_float4(0.f, 0.f, 0.f, 0.f), v1 = v0;
      if (ok) {
        v0 = *(const float4*)(rp + ks * 32 + G * 8);
        v1 = *(const float4*)(rp + ks * 32 + G * 8 + 4);
      }
      unsigned short h, lo;
      split_bf16(v0.x, h, lo); aFh[m][ks][0] = (short)h; aFl[m][ks][0] = (short)lo;
      split_bf16(v0.y, h, lo); aFh[m][ks][1] = (short)h; aFl[m][ks][1] = (short)lo;
      split_bf16(v0.z, h, lo); aFh[m][ks][2] = (short)h; aFl[m][ks][2] = (short)lo;
      split_bf16(v0.w, h, lo); aFh[m][ks][3] = (short)h; aFl[m][ks][3] = (short)lo;
      split_bf16(v1.x, h, lo); aFh[m][ks][4] = (short)h; aFl[m][ks][4] = (short)lo;
      split_bf16(v1.y, h, lo); aFh[m][ks][5] = (short)h; aFl[m][ks][5] = (short)lo;
      split_bf16(v1.z, h, lo); aFh[m][ks][6] = (short)h; aFl[m][ks][6] = (short)lo;
      split_bf16(v1.w, h, lo); aFh[m][ks][7] = (short)h; aFl[m][ks][7] = (short)lo;
    }
  }

  const bf16x8* W1Fv = (const bf16x8*)W1F;
  const bf16x8* W2Fv = (const bf16x8*)W2F;

  f32x4 acc2[2][4];
#pragma unroll
  for (int m = 0; m < 2; m++)
#pragma unroll
    for (int n = 0; n < 4; n++) acc2[m][n] = (f32x4){0.f, 0.f, 0.f, 0.f};

  for (int jt = 0; jt < 8; jt++) {
    // ---- prefetch this jt's W2 fragments (no TS dependency; lands early) ----
    bf16x8 w2h[2][4], w2l[2][4];
#pragma unroll
    for (int ks = 0; ks < 2; ks++)
#pragma unroll
      for (int n = 0; n < 4; n++) {
        int fi2 = (jt * 2 + ks) * 4 + n;
        w2h[ks][n] = W2Fv[(size_t)(fi2 * 2 + 0) * 64 + l];
        w2l[ks][n] = W2Fv[(size_t)(fi2 * 2 + 1) * 64 + l];
      }
    // --- gemm1 slab: cols jt*64 + n*16 + lr, K = 128; per-ks batched loads ---
    f32x4 acc1[2][4];
#pragma unroll
    for (int m = 0; m < 2; m++)
#pragma unroll
      for (int n = 0; n < 4; n++) acc1[m][n] = (f32x4){0.f, 0.f, 0.f, 0.f};
#pragma unroll
    for (int ks = 0; ks < 4; ks++) {
      bf16x8 bh[4], bl[4];
#pragma unroll
      for (int n = 0; n < 4; n++) {
        int fi = (jt * 4 + n) * 4 + ks;
        bh[n] = W1Fv[(size_t)(fi * 2 + 0) * 64 + l];
        bl[n] = W1Fv[(size_t)(fi * 2 + 1) * 64 + l];
      }
#pragma unroll
      for (int n = 0; n < 4; n++) {
#pragma unroll
        for (int m = 0; m < 2; m++) {
          acc1[m][n] = __builtin_amdgcn_mfma_f32_16x16x32_bf16(aFh[m][ks], bh[n], acc1[m][n], 0, 0, 0);
          acc1[m][n] = __builtin_amdgcn_mfma_f32_16x16x32_bf16(aFl[m][ks], bh[n], acc1[m][n], 0, 0, 0);
          acc1[m][n] = __builtin_amdgcn_mfma_f32_16x16x32_bf16(aFh[m][ks], bl[n], acc1[m][n], 0, 0, 0);
        }
      }
    }
    // --- epilogue: bias + relu, split, write TS (own stripe; no barrier) ---
#pragma unroll
    for (int n = 0; n < 4; n++) {
      float bv = b1[jt * 64 + n * 16 + lr];
#pragma unroll
      for (int m = 0; m < 2; m++) {
#pragma unroll
        for (int r = 0; r < 4; r++) {
          float vv = fmaxf(acc1[m][n][r] + bv, 0.f);
          unsigned short hh, ll;
          split_bf16(vv, hh, ll);
          int rowL = w * 32 + m * 16 + G * 4 + r;
          int colS = (n * 16 + lr) ^ ((rowL & 7) << 2);
          TS[rowL][colS] = (unsigned)hh | ((unsigned)ll << 16);
        }
      }
    }
    // --- gemm2 partial: acc2 += out1_slab @ W2[jt*64 .. +63, :] ---
#pragma unroll
    for (int ks = 0; ks < 2; ks++) {
      int kl = ks * 32 + G * 8;
      bf16x8 a2h[2], a2l[2];
#pragma unroll
      for (int m = 0; m < 2; m++) {
        int rowA = w * 32 + m * 16 + lr;
        int sw2 = (rowA & 7) << 2;
        uint4 q0 = *(const uint4*)&TS[rowA][(kl + 0) ^ sw2];
        uint4 q1 = *(const uint4*)&TS[rowA][(kl + 4) ^ sw2];
        a2h[m][0] = (short)(q0.x & 0xffff); a2l[m][0] = (short)(q0.x >> 16);
        a2h[m][1] = (short)(q0.y & 0xffff); a2l[m][1] = (short)(q0.y >> 16);
        a2h[m][2] = (short)(q0.z & 0xffff); a2l[m][2] = (short)(q0.z >> 16);
        a2h[m][3] = (short)(q0.w & 0xffff); a2l[m][3] = (short)(q0.w >> 16);
        a2h[m][4] = (short)(q1.x & 0xffff); a2l[m][4] = (short)(q1.x >> 16);
        a2h[m][5] = (short)(q1.y & 0xffff); a2l[m][5] = (short)(q1.y >> 16);
        a2h[m][6] = (short)(q1.z & 0xffff); a2l[m][6] = (short)(q1.z >> 16);
        a2h[m][7] = (short)(q1.w & 0xffff); a2l[m][7] = (short)(q1.w >> 16);
      }
#pragma unroll
      for (int n = 0; n < 4; n++) {
#pragma unroll
        for (int m = 0; m < 2; m++) {
          acc2[m][n] = __builtin_amdgcn_mfma_f32_16x16x32_bf16(a2h[m], w2h[ks][n], acc2[m][n], 0, 0, 0);
          acc2[m][n] = __builtin_amdgcn_mfma_f32_16x16x32_bf16(a2l[m], w2h[ks][n], acc2[m][n], 0, 0, 0);
          acc2[m][n] = __builtin_amdgcn_mfma_f32_16x16x32_bf16(a2h[m], w2l[ks][n], acc2[m][n], 0, 0, 0);
        }
      }
    }
  }

  // ---- epilogue: h2 write + fused layer-2 node scores ----
#pragma unroll
  for (int m = 0; m < 2; m++) {
#pragma unroll
    for (int r = 0; r < 4; r++) {
      int grow = base + m * 16 + G * 4 + r;
      if (grow < N_NODES) {
#pragma unroll
        for (int n = 0; n < 4; n++)
          h2[(size_t)grow * OUT2 + n * 16 + lr] = acc2[m][n][r];
      }
      float sp = 0.f, dp = 0.f;
#pragma unroll
      for (int n = 0; n < 4; n++) {
        float v = acc2[m][n][r];
        sp += v * a2s[n * 16 + lr];
        dp += v * a2d[n * 16 + lr];
      }
#pragma unroll
      for (int o = 1; o < 16; o <<= 1) {
        sp += __shfl_xor(sp, o, 64);
        dp += __shfl_xor(dp, o, 64);
      }
      if (lr == 0 && grow < N_NODES) { as2[grow] = sp; ad2[grow] = dp; }
    }
  }
}

// ---- fused layer-2 softmax + aggregation + relu + FC head ------------------
__global__ void sm_agg2_final(const int* __restrict__ row_ptr, const int* __restrict__ csr_src,
                              const float* __restrict__ as_, const float* __restrict__ ad_,
                              const float* __restrict__ h2, const float* __restrict__ b2,
                              const float* __restrict__ fcW, const float* __restrict__ fcb,
                              float* __restrict__ out) {
  int wid = (blockIdx.x * blockDim.x + threadIdx.x) >> 6;
  int lane = threadIdx.x & 63;
  if (wid >= N_NODES) return;
  int beg = row_ptr[wid], end = row_ptr[wid + 1];
  int deg = end - beg;
  float adv = ad_[wid];
  float acc = 0.f;
  if (deg <= 64) {
    int s = 0; float sc = -3.4e38f;
    if (lane < deg) { s = csr_src[beg + lane]; sc = leaky(as_[s] + adv); }
    float m = wave_max(sc);
    float ex = (lane < deg) ? __expf(sc - m) : 0.f;
    float sum = wave_sum(ex);
    float a = ex / sum;
    int kk = 0;
    for (; kk + 8 <= deg; kk += 8) {
      float w0 = __shfl(a, kk, 64),     w1 = __shfl(a, kk + 1, 64);
      float w2 = __shfl(a, kk + 2, 64), w3 = __shfl(a, kk + 3, 64);
      float w4 = __shfl(a, kk + 4, 64), w5 = __shfl(a, kk + 5, 64);
      float w6 = __shfl(a, kk + 6, 64), w7 = __shfl(a, kk + 7, 64);
      int s0 = __shfl(s, kk, 64),     s1 = __shfl(s, kk + 1, 64);
      int s2 = __shfl(s, kk + 2, 64), s3 = __shfl(s, kk + 3, 64);
      int s4 = __shfl(s, kk + 4, 64), s5 = __shfl(s, kk + 5, 64);
      int s6 = __shfl(s, kk + 6, 64), s7 = __shfl(s, kk + 7, 64);
      float r0 = h2[(size_t)s0 * OUT2 + lane];
      float r1 = h2[(size_t)s1 * OUT2 + lane];
      float r2 = h2[(size_t)s2 * OUT2 + lane];
      float r3 = h2[(size_t)s3 * OUT2 + lane];
      float r4 = h2[(size_t)s4 * OUT2 + lane];
      float r5 = h2[(size_t)s5 * OUT2 + lane];
      float r6 = h2[(size_t)s6 * OUT2 + lane];
      float r7 = h2[(size_t)s7 * OUT2 + lane];
      acc += w0 * r0 + w1 * r1 + w2 * r2 + w3 * r3
           + w4 * r4 + w5 * r5 + w6 * r6 + w7 * r7;
    }
    for (; kk + 4 <= deg; kk += 4) {
      float w0 = __shfl(a, kk, 64),     w1 = __shfl(a, kk + 1, 64);
      float w2 = __shfl(a, kk + 2, 64), w3 = __shfl(a, kk + 3, 64);
      int s0 = __shfl(s, kk, 64),     s1 = __shfl(s, kk + 1, 64);
      int s2 = __shfl(s, kk + 2, 64), s3 = __shfl(s, kk + 3, 64);
      float r0 = h2[(size_t)s0 * OUT2 + lane];
      float r1 = h2[(size_t)s1 * OUT2 + lane];
      float r2 = h2[(size_t)s2 * OUT2 + lane];
      float r3 = h2[(size_t)s3 * OUT2 + lane];
      acc += w0 * r0 + w1 * r1 + w2 * r2 + w3 * r3;
    }
    for (; kk < deg; kk++) {
      float w = __shfl(a, kk, 64);
      int sv = __shfl(s, kk, 64);
      acc += w * h2[(size_t)sv * OUT2 + lane];
    }
  } else {
    float m = -3.4e38f;
    for (int k = beg + lane; k < end; k += 64)
      m = fmaxf(m, leaky(as_[csr_src[k]] + adv));
    m = wave_max(m);
    float sum = 0.f;
    for (int k = beg + lane; k < end; k += 64)
      sum += __expf(leaky(as_[csr_src[k]] + adv) - m);
    sum = wave_sum(sum);
    float inv = 1.f / sum;
    for (int k = beg; k < end; k++) {
      int sv = csr_src[k];
      float w = __expf(leaky(as_[sv] + adv) - m) * inv;
      acc += w * h2[(size_t)sv * OUT2 + lane];
    }
  }
  float v = fmaxf(acc + b2[lane], 0.f);
  float2 fw = ((const float2*)fcW)[lane];
  float f0 = wave_sum(v * fw.x);
  float f1 = wave_sum(v * fw.y);
  if (lane == 0) {
    out[(size_t)wid * 2 + 0] = f0 + fcb[0];
    out[(size_t)wid * 2 + 1] = f1 + fcb[1];
  }
}

extern "C" void kernel_launch(void* const* d_in, const int* in_sizes, int n_in,
                              void* d_out, int out_size, void* d_ws, size_t ws_size,
                              hipStream_t stream) {
  const float* x    = (const float*)d_in[0];
  const int*   ei   = (const int*)d_in[1];
  const float* W1   = (const float*)d_in[2];
  const float* a1s  = (const float*)d_in[3];
  const float* a1d  = (const float*)d_in[4];
  const float* b1   = (const float*)d_in[5];
  const float* W2   = (const float*)d_in[6];
  const float* a2s  = (const float*)d_in[7];
  const float* a2d  = (const float*)d_in[8];
  const float* b2   = (const float*)d_in[9];
  const float* fcW  = (const float*)d_in[10];
  const float* fcb  = (const float*)d_in[11];
  float* out = (float*)d_out;

  char* p = (char*)d_ws;
  float* xa    = (float*)p; p += (size_t)N_NODES * IN_C * 4;
  float* h2    = (float*)p; p += (size_t)N_NODES * OUT2 * 4;
  float* as1   = (float*)p; p += (size_t)N_NODES * 4;   // reused for layer-2 scores
  float* ad1   = (float*)p; p += (size_t)N_NODES * 4;
  float* w1s   = (float*)p; p += 256 * 4;
  float* w1d   = (float*)p; p += 256 * 4;
  int* row_ptr = (int*)p;   p += (size_t)(N_NODES + 4) * 4;
  int* deg     = (int*)p;   p += (size_t)N_NODES * 4;   // also reused as cursor
  int* bsum    = (int*)p;   p += 64 * 4;
  int* boff    = (int*)p;   p += 64 * 4;
  int* csr_src = (int*)p;   p += (size_t)E_TOT * 4;
  unsigned short* W1F = (unsigned short*)p; p += (size_t)128 * 2 * 64 * 8 * 2;  // 256KB
  unsigned short* W2F = (unsigned short*)p; p += (size_t)64 * 2 * 64 * 8 * 2;   // 128KB

  const int edge_blocks = (E_TOT + 255) / 256;
  const int node_wave_blocks = (N_NODES + 3) / 4;   // 4 waves per 256-thread block
  const int m_tiles64 = (N_NODES + 63) / 64;        // 782 blocks of 128 threads
  const int scan_blocks = (N_NODES + 1023) / 1024;  // 49

  // ---- CSR build + weight prep ----
  hipMemsetAsync(deg, 0, (size_t)N_NODES * 4, stream);
  count_deg<<<edge_blocks, 256, 0, stream>>>(ei, deg);
  scanA<<<scan_blocks, 1024, 0, stream>>>(deg, bsum);
  scanB<<<1, 64, 0, stream>>>(bsum, boff, scan_blocks);
  scanC<<<scan_blocks, 1024, 0, stream>>>(deg, boff, row_ptr);
  hipMemsetAsync(deg, 0, (size_t)N_NODES * 4, stream);
  fill_csr<<<edge_blocks, 256, 0, stream>>>(ei, row_ptr, deg, csr_src);
  prep_weights<<<80, 256, 0, stream>>>(W1, W2, a1s, a1d, W1F, W2F, w1s, w1d);

  // ---- layer 1: scores -> fused softmax+aggregate (input space) ----
  node_scores128<<<node_wave_blocks, 256, 0, stream>>>(x, w1s, w1d, as1, ad1);
  sm_agg1<<<node_wave_blocks, 256, 0, stream>>>(row_ptr, csr_src, as1, ad1, x, xa);

  // ---- fused gemm1+relu+gemm2+layer-2 scores (bf16-split MFMA, pipelined) ----
  fused_gemm_mfma<<<m_tiles64, 128, 0, stream>>>(xa, W1F, b1, W2F,
                                                 a2s, a2d, h2, as1, ad1);

  // ---- layer 2: fused softmax+aggregate+relu+head ----
  sm_agg2_final<<<node_wave_blocks, 256, 0, stream>>>(row_ptr, csr_src, as1, ad1, h2, b2,
                                                      fcW, fcb, out);
}

// Round 11
// 256.894 us; speedup vs baseline: 1.6442x; 1.0389x over previous
//
#include <hip/hip_runtime.h>

#define N_NODES 50000
#define N_EDGES 400000
#define E_TOT   (N_EDGES + N_NODES)   // 450000, self-loops appended
#define IN_C 128
#define HID  512
#define OUT2 64
#define NEG_SLOPE 0.2f

typedef short bf16x8 __attribute__((ext_vector_type(8)));
typedef float f32x4  __attribute__((ext_vector_type(4)));

__device__ __forceinline__ float wave_sum(float v) {
#pragma unroll
  for (int o = 32; o > 0; o >>= 1) v += __shfl_xor(v, o, 64);
  return v;
}
__device__ __forceinline__ int wave_sum_i(int v) {
#pragma unroll
  for (int o = 32; o > 0; o >>= 1) v += __shfl_xor(v, o, 64);
  return v;
}
__device__ __forceinline__ float wave_max(float v) {
#pragma unroll
  for (int o = 32; o > 0; o >>= 1) v = fmaxf(v, __shfl_xor(v, o, 64));
  return v;
}
__device__ __forceinline__ float leaky(float t) {
  return (t > 0.f) ? t : NEG_SLOPE * t;
}

// fp32 -> bf16 (RNE) and hi/lo split: x ~= hi + lo, |err| <= 2^-18 |x|
__device__ __forceinline__ unsigned short bf16_rne(float x) {
  unsigned u = __float_as_uint(x);
  u += 0x7fffu + ((u >> 16) & 1u);
  return (unsigned short)(u >> 16);
}
__device__ __forceinline__ void split_bf16(float x, unsigned short& h, unsigned short& l) {
  h = bf16_rne(x);
  float hf = __uint_as_float(((unsigned)h) << 16);
  l = bf16_rne(x - hf);
}

// async global -> LDS, 16B per lane; LDS dst is wave-uniform base (HW adds lane*16)
__device__ __forceinline__ void gload_lds16(const void* g, void* lds) {
  __builtin_amdgcn_global_load_lds(
      (const __attribute__((address_space(1))) unsigned int*)g,
      (__attribute__((address_space(3))) unsigned int*)lds, 16, 0, 0);
}

// src/dst of logical edge e (e >= N_EDGES are self-loops)
__device__ __forceinline__ int esrc(const int* __restrict__ ei, int e) {
  return (e < N_EDGES) ? ei[e] : (e - N_EDGES);
}
__device__ __forceinline__ int edst(const int* __restrict__ ei, int e) {
  return (e < N_EDGES) ? ei[N_EDGES + e] : (e - N_EDGES);
}

// ---- CSR build -------------------------------------------------------------
__global__ void count_deg(const int* __restrict__ ei, int* __restrict__ deg) {
  int e = blockIdx.x * blockDim.x + threadIdx.x;
  if (e >= E_TOT) return;
  atomicAdd(&deg[edst(ei, e)], 1);
}

__global__ void scanA(const int* __restrict__ deg, int* __restrict__ bsum) {
  __shared__ int ws[16];
  int t = threadIdx.x, lane = t & 63, w = t >> 6;
  int i = blockIdx.x * 1024 + t;
  int v = (i < N_NODES) ? deg[i] : 0;
  int s = wave_sum_i(v);
  if (lane == 0) ws[w] = s;
  __syncthreads();
  if (t == 0) {
    int tot = 0;
#pragma unroll
    for (int k = 0; k < 16; k++) tot += ws[k];
    bsum[blockIdx.x] = tot;
  }
}

__global__ void scanB(const int* __restrict__ bsum, int* __restrict__ boff, int nb) {
  int lane = threadIdx.x;  // 64 threads
  int v = (lane < nb) ? bsum[lane] : 0;
  int sc = v;
#pragma unroll
  for (int off = 1; off < 64; off <<= 1) {
    int u = __shfl_up(sc, off, 64);
    if (lane >= off) sc += u;
  }
  if (lane < nb) boff[lane] = sc - v;  // exclusive
}

__global__ void scanC(const int* __restrict__ deg, const int* __restrict__ boff,
                      int* __restrict__ row_ptr) {
  __shared__ int ws[16];
  int t = threadIdx.x, lane = t & 63, w = t >> 6;
  int i = blockIdx.x * 1024 + t;
  int v = (i < N_NODES) ? deg[i] : 0;
  int sc = v;
#pragma unroll
  for (int off = 1; off < 64; off <<= 1) {
    int u = __shfl_up(sc, off, 64);
    if (lane >= off) sc += u;
  }
  if (lane == 63) ws[w] = sc;
  __syncthreads();
  if (w == 0 && lane < 16) {
    int u = ws[lane];
#pragma unroll
    for (int off = 1; off < 16; off <<= 1) {
      int uu = __shfl_up(u, off, 64);
      if (lane >= off) u += uu;
    }
    ws[lane] = u;
  }
  __syncthreads();
  int excl = ((w > 0) ? ws[w - 1] : 0) + boff[blockIdx.x];
  if (i < N_NODES) row_ptr[i + 1] = sc + excl;
  if (blockIdx.x == 0 && t == 0) row_ptr[0] = 0;
}

__global__ void fill_csr(const int* __restrict__ ei, const int* __restrict__ row_ptr,
                         int* __restrict__ cursor, int* __restrict__ csr_src) {
  int e = blockIdx.x * blockDim.x + threadIdx.x;
  if (e >= E_TOT) return;
  int d = edst(ei, e);
  int pos = atomicAdd(&cursor[d], 1);
  csr_src[row_ptr[d] + pos] = esrc(ei, e);
}

// ---- merged weight prep: W1F frags + W2F frags + matvec_w1 -----------------
// blocks [0,32): W1 frags; [32,48): W2 frags; [48,80): w1s/w1d matvec
__global__ void prep_weights(const float* __restrict__ W1, const float* __restrict__ W2,
                             const float* __restrict__ a1s, const float* __restrict__ a1d,
                             unsigned short* __restrict__ W1F, unsigned short* __restrict__ W2F,
                             float* __restrict__ w1s, float* __restrict__ w1d) {
  int b = blockIdx.x;
  if (b < 32) {
    int t = b * 256 + threadIdx.x;   // 8192 lane-tasks
    int fi = t >> 6, l = t & 63;
    int ks = fi & 3, n = (fi >> 2) & 3, jt = fi >> 4;
    int col = jt * 64 + n * 16 + (l & 15);
    int k0 = ks * 32 + (l >> 4) * 8;
    unsigned short hv[8], lv[8];
#pragma unroll
    for (int e = 0; e < 8; e++)
      split_bf16(W1[(size_t)(k0 + e) * HID + col], hv[e], lv[e]);
    unsigned short* ph = W1F + ((size_t)(fi * 2 + 0) * 64 + l) * 8;
    unsigned short* pl = W1F + ((size_t)(fi * 2 + 1) * 64 + l) * 8;
#pragma unroll
    for (int e = 0; e < 8; e++) { ph[e] = hv[e]; pl[e] = lv[e]; }
  } else if (b < 48) {
    int t = (b - 32) * 256 + threadIdx.x;   // 4096 lane-tasks
    int fi = t >> 6, l = t & 63;
    int n = fi & 3, ks = (fi >> 2) & 1, jt = fi >> 3;
    int col = n * 16 + (l & 15);
    int k0 = jt * 64 + ks * 32 + (l >> 4) * 8;
    unsigned short hv[8], lv[8];
#pragma unroll
    for (int e = 0; e < 8; e++)
      split_bf16(W2[(size_t)(k0 + e) * OUT2 + col], hv[e], lv[e]);
    unsigned short* ph = W2F + ((size_t)(fi * 2 + 0) * 64 + l) * 8;
    unsigned short* pl = W2F + ((size_t)(fi * 2 + 1) * 64 + l) * 8;
#pragma unroll
    for (int e = 0; e < 8; e++) { ph[e] = hv[e]; pl[e] = lv[e]; }
  } else {
    int wid = ((b - 48) * 256 + threadIdx.x) >> 6;
    int lane = threadIdx.x & 63;
    if (wid >= IN_C) return;
    const float* row = W1 + (size_t)wid * HID;
    float s = 0.f, d = 0.f;
#pragma unroll
    for (int j0 = 0; j0 < HID; j0 += 64) {
      float w = row[j0 + lane];
      s += w * a1s[j0 + lane];
      d += w * a1d[j0 + lane];
    }
    s = wave_sum(s); d = wave_sum(d);
    if (lane == 0) { w1s[wid] = s; w1d[wid] = d; }
  }
}

// alpha_s[i] = x[i].w1s ; alpha_d[i] = x[i].w1d  (one wave per node, float2)
__global__ void node_scores128(const float* __restrict__ x, const float* __restrict__ ws,
                               const float* __restrict__ wd, float* __restrict__ as_,
                               float* __restrict__ ad_) {
  int wid = (blockIdx.x * blockDim.x + threadIdx.x) >> 6;
  int lane = threadIdx.x & 63;
  if (wid >= N_NODES) return;
  float2 v = ((const float2*)(x + (size_t)wid * IN_C))[lane];
  float2 w1 = ((const float2*)ws)[lane];
  float2 w2 = ((const float2*)wd)[lane];
  float s = wave_sum(v.x * w1.x + v.y * w1.y);
  float d = wave_sum(v.x * w2.x + v.y * w2.y);
  if (lane == 0) { as_[wid] = s; ad_[wid] = d; }
}

// ---- fused segment-softmax + aggregation, layer 1 (128 ch, input space) ----
// gather loop 8x-unrolled: covers deg~9 in one batch of in-flight loads
__global__ void sm_agg1(const int* __restrict__ row_ptr, const int* __restrict__ csr_src,
                        const float* __restrict__ as_, const float* __restrict__ ad_,
                        const float* __restrict__ x, float* __restrict__ xa) {
  int wid = (blockIdx.x * blockDim.x + threadIdx.x) >> 6;
  int lane = threadIdx.x & 63;
  if (wid >= N_NODES) return;
  int beg = row_ptr[wid], end = row_ptr[wid + 1];
  int deg = end - beg;
  float adv = ad_[wid];
  const float2* x2 = (const float2*)x;
  float2 acc = make_float2(0.f, 0.f);
  if (deg <= 64) {
    int s = 0; float sc = -3.4e38f;
    if (lane < deg) { s = csr_src[beg + lane]; sc = leaky(as_[s] + adv); }
    float m = wave_max(sc);
    float ex = (lane < deg) ? __expf(sc - m) : 0.f;
    float sum = wave_sum(ex);
    float a = ex / sum;
    int kk = 0;
    for (; kk + 8 <= deg; kk += 8) {
      float w0 = __shfl(a, kk, 64),     w1 = __shfl(a, kk + 1, 64);
      float w2 = __shfl(a, kk + 2, 64), w3 = __shfl(a, kk + 3, 64);
      float w4 = __shfl(a, kk + 4, 64), w5 = __shfl(a, kk + 5, 64);
      float w6 = __shfl(a, kk + 6, 64), w7 = __shfl(a, kk + 7, 64);
      int s0 = __shfl(s, kk, 64),     s1 = __shfl(s, kk + 1, 64);
      int s2 = __shfl(s, kk + 2, 64), s3 = __shfl(s, kk + 3, 64);
      int s4 = __shfl(s, kk + 4, 64), s5 = __shfl(s, kk + 5, 64);
      int s6 = __shfl(s, kk + 6, 64), s7 = __shfl(s, kk + 7, 64);
      float2 r0 = x2[(size_t)s0 * 64 + lane];
      float2 r1 = x2[(size_t)s1 * 64 + lane];
      float2 r2 = x2[(size_t)s2 * 64 + lane];
      float2 r3 = x2[(size_t)s3 * 64 + lane];
      float2 r4 = x2[(size_t)s4 * 64 + lane];
      float2 r5 = x2[(size_t)s5 * 64 + lane];
      float2 r6 = x2[(size_t)s6 * 64 + lane];
      float2 r7 = x2[(size_t)s7 * 64 + lane];
      acc.x += w0 * r0.x + w1 * r1.x + w2 * r2.x + w3 * r3.x
             + w4 * r4.x + w5 * r5.x + w6 * r6.x + w7 * r7.x;
      acc.y += w0 * r0.y + w1 * r1.y + w2 * r2.y + w3 * r3.y
             + w4 * r4.y + w5 * r5.y + w6 * r6.y + w7 * r7.y;
    }
    for (; kk + 4 <= deg; kk += 4) {
      float w0 = __shfl(a, kk, 64),     w1 = __shfl(a, kk + 1, 64);
      float w2 = __shfl(a, kk + 2, 64), w3 = __shfl(a, kk + 3, 64);
      int s0 = __shfl(s, kk, 64),     s1 = __shfl(s, kk + 1, 64);
      int s2 = __shfl(s, kk + 2, 64), s3 = __shfl(s, kk + 3, 64);
      float2 r0 = x2[(size_t)s0 * 64 + lane];
      float2 r1 = x2[(size_t)s1 * 64 + lane];
      float2 r2 = x2[(size_t)s2 * 64 + lane];
      float2 r3 = x2[(size_t)s3 * 64 + lane];
      acc.x += w0 * r0.x + w1 * r1.x + w2 * r2.x + w3 * r3.x;
      acc.y += w0 * r0.y + w1 * r1.y + w2 * r2.y + w3 * r3.y;
    }
    for (; kk < deg; kk++) {
      float w = __shfl(a, kk, 64);
      int sv = __shfl(s, kk, 64);
      float2 r = x2[(size_t)sv * 64 + lane];
      acc.x += w * r.x; acc.y += w * r.y;
    }
  } else {  // fallback (kept for correctness on any graph)
    float m = -3.4e38f;
    for (int k = beg + lane; k < end; k += 64)
      m = fmaxf(m, leaky(as_[csr_src[k]] + adv));
    m = wave_max(m);
    float sum = 0.f;
    for (int k = beg + lane; k < end; k += 64)
      sum += __expf(leaky(as_[csr_src[k]] + adv) - m);
    sum = wave_sum(sum);
    float inv = 1.f / sum;
    for (int k = beg; k < end; k++) {
      int sv = csr_src[k];
      float w = __expf(leaky(as_[sv] + adv) - m) * inv;
      float2 r = x2[(size_t)sv * 64 + lane];
      acc.x += w * r.x; acc.y += w * r.y;
    }
  }
  ((float2*)(xa + (size_t)wid * IN_C))[lane] = acc;
}

// ---- fused gemm1(relu) + gemm2 + layer-2 node scores, bf16-split MFMA ------
// 4 waves x 32 rows = 128 rows/block. Per jt, the 48 B fragments (48KB) are
// cooperatively staged into LDS via async global_load_lds (12 issues/wave,
// no dest VGPR -> scheduler can't serialize), then SHARED by all 4 waves.
__launch_bounds__(256, 2)
__global__ void fused_gemm_mfma(const float* __restrict__ xa,
                                const unsigned short* __restrict__ W1F,
                                const float* __restrict__ b1,
                                const unsigned short* __restrict__ W2F,
                                const float* __restrict__ a2s, const float* __restrict__ a2d,
                                float* __restrict__ h2, float* __restrict__ as2,
                                float* __restrict__ ad2) {
  __shared__ uint4 Bst[48 * 64];        // 48KB: frag f at [f*64 .. f*64+63]
  __shared__ unsigned int TS[128][64];  // 32KB; wave w owns rows w*32..w*32+31
  int t = threadIdx.x;
  int w = t >> 6;        // wave id (0..3)
  int l = t & 63;
  int lr = l & 15;       // row/col within 16-tile
  int G  = l >> 4;       // k-group
  int base = blockIdx.x * 128 + w * 32;  // first node row of this wave

  // ---- prologue: A fragments global -> registers, fp32 -> hi/lo bf16 ----
  bf16x8 aFh[2][4], aFl[2][4];
#pragma unroll
  for (int m = 0; m < 2; m++) {
    int grow = base + m * 16 + lr;
    bool ok = (grow < N_NODES);
    const float* rp = xa + (size_t)grow * IN_C;
#pragma unroll
    for (int ks = 0; ks < 4; ks++) {
      float4 v0 = make_float4(0.f, 0.f, 0.f, 0.f), v1 = v0;
      if (ok) {
        v0 = *(const float4*)(rp + ks * 32 + G * 8);
        v1 = *(const float4*)(rp + ks * 32 + G * 8 + 4);
      }
      unsigned short h, lo;
      split_bf16(v0.x, h, lo); aFh[m][ks][0] = (short)h; aFl[m][ks][0] = (short)lo;
      split_bf16(v0.y, h, lo); aFh[m][ks][1] = (short)h; aFl[m][ks][1] = (short)lo;
      split_bf16(v0.z, h, lo); aFh[m][ks][2] = (short)h; aFl[m][ks][2] = (short)lo;
      split_bf16(v0.w, h, lo); aFh[m][ks][3] = (short)h; aFl[m][ks][3] = (short)lo;
      split_bf16(v1.x, h, lo); aFh[m][ks][4] = (short)h; aFl[m][ks][4] = (short)lo;
      split_bf16(v1.y, h, lo); aFh[m][ks][5] = (short)h; aFl[m][ks][5] = (short)lo;
      split_bf16(v1.z, h, lo); aFh[m][ks][6] = (short)h; aFl[m][ks][6] = (short)lo;
      split_bf16(v1.w, h, lo); aFh[m][ks][7] = (short)h; aFl[m][ks][7] = (short)lo;
    }
  }

  f32x4 acc2[2][4];
#pragma unroll
  for (int m = 0; m < 2; m++)
#pragma unroll
    for (int n = 0; n < 4; n++) acc2[m][n] = (f32x4){0.f, 0.f, 0.f, 0.f};

  const char* ldsB = (const char*)&Bst[0];

  for (int jt = 0; jt < 8; jt++) {
    __syncthreads();   // all waves done reading Bst for jt-1
    // ---- stage this jt's 48 B fragments: wave w stages f = w*12 .. w*12+11 ----
#pragma unroll
    for (int i = 0; i < 12; i++) {
      int f = w * 12 + i;
      const char* src;
      if (f < 32) {            // W1 frag: f = (n<<3)|(ks<<1)|hl
        int hl = f & 1, ks = (f >> 1) & 3, n = f >> 3;
        int fi = (jt * 4 + n) * 4 + ks;
        src = (const char*)W1F + ((size_t)(fi * 2 + hl) * 64 + l) * 16;
      } else {                 // W2 frag: f-32 = (ks<<3)|(n<<1)|hl
        int f2 = f - 32;
        int hl = f2 & 1, n = (f2 >> 1) & 3, ks = f2 >> 3;
        int fi2 = (jt * 2 + ks) * 4 + n;
        src = (const char*)W2F + ((size_t)(fi2 * 2 + hl) * 64 + l) * 16;
      }
      gload_lds16(src, (void*)((char*)&Bst[0] + (size_t)f * 1024));
    }
    __syncthreads();   // drains vmcnt -> staged data visible

    // --- gemm1 slab: cols jt*64 + n*16 + lr, K = 128 ---
    f32x4 acc1[2][4];
#pragma unroll
    for (int m = 0; m < 2; m++)
#pragma unroll
      for (int n = 0; n < 4; n++) acc1[m][n] = (f32x4){0.f, 0.f, 0.f, 0.f};
#pragma unroll
    for (int ks = 0; ks < 4; ks++) {
#pragma unroll
      for (int n = 0; n < 4; n++) {
        const char* bp = ldsB + (size_t)((n << 3) | (ks << 1)) * 1024 + (size_t)l * 16;
        bf16x8 b_h = *(const bf16x8*)bp;
        bf16x8 b_l = *(const bf16x8*)(bp + 1024);
#pragma unroll
        for (int m = 0; m < 2; m++) {
          acc1[m][n] = __builtin_amdgcn_mfma_f32_16x16x32_bf16(aFh[m][ks], b_h, acc1[m][n], 0, 0, 0);
          acc1[m][n] = __builtin_amdgcn_mfma_f32_16x16x32_bf16(aFl[m][ks], b_h, acc1[m][n], 0, 0, 0);
          acc1[m][n] = __builtin_amdgcn_mfma_f32_16x16x32_bf16(aFh[m][ks], b_l, acc1[m][n], 0, 0, 0);
        }
      }
    }
    // --- epilogue: bias + relu, split, write TS (own stripe; no barrier) ---
#pragma unroll
    for (int n = 0; n < 4; n++) {
      float bv = b1[jt * 64 + n * 16 + lr];
#pragma unroll
      for (int m = 0; m < 2; m++) {
#pragma unroll
        for (int r = 0; r < 4; r++) {
          float vv = fmaxf(acc1[m][n][r] + bv, 0.f);
          unsigned short hh, ll;
          split_bf16(vv, hh, ll);
          int rowL = w * 32 + m * 16 + G * 4 + r;
          int colS = (n * 16 + lr) ^ ((rowL & 7) << 2);
          TS[rowL][colS] = (unsigned)hh | ((unsigned)ll << 16);
        }
      }
    }
    // --- gemm2 partial: acc2 += out1_slab @ W2[jt*64 .. +63, :] ---
#pragma unroll
    for (int ks = 0; ks < 2; ks++) {
      int kl = ks * 32 + G * 8;
      bf16x8 a2h[2], a2l[2];
#pragma unroll
      for (int m = 0; m < 2; m++) {
        int rowA = w * 32 + m * 16 + lr;
        int sw2 = (rowA & 7) << 2;
        uint4 q0 = *(const uint4*)&TS[rowA][(kl + 0) ^ sw2];
        uint4 q1 = *(const uint4*)&TS[rowA][(kl + 4) ^ sw2];
        a2h[m][0] = (short)(q0.x & 0xffff); a2l[m][0] = (short)(q0.x >> 16);
        a2h[m][1] = (short)(q0.y & 0xffff); a2l[m][1] = (short)(q0.y >> 16);
        a2h[m][2] = (short)(q0.z & 0xffff); a2l[m][2] = (short)(q0.z >> 16);
        a2h[m][3] = (short)(q0.w & 0xffff); a2l[m][3] = (short)(q0.w >> 16);
        a2h[m][4] = (short)(q1.x & 0xffff); a2l[m][4] = (short)(q1.x >> 16);
        a2h[m][5] = (short)(q1.y & 0xffff); a2l[m][5] = (short)(q1.y >> 16);
        a2h[m][6] = (short)(q1.z & 0xffff); a2l[m][6] = (short)(q1.z >> 16);
        a2h[m][7] = (short)(q1.w & 0xffff); a2l[m][7] = (short)(q1.w >> 16);
      }
#pragma unroll
      for (int n = 0; n < 4; n++) {
        const char* bp = ldsB + (size_t)(32 + ((ks << 3) | (n << 1))) * 1024 + (size_t)l * 16;
        bf16x8 b_h = *(const bf16x8*)bp;
        bf16x8 b_l = *(const bf16x8*)(bp + 1024);
#pragma unroll
        for (int m = 0; m < 2; m++) {
          acc2[m][n] = __builtin_amdgcn_mfma_f32_16x16x32_bf16(a2h[m], b_h, acc2[m][n], 0, 0, 0);
          acc2[m][n] = __builtin_amdgcn_mfma_f32_16x16x32_bf16(a2l[m], b_h, acc2[m][n], 0, 0, 0);
          acc2[m][n] = __builtin_amdgcn_mfma_f32_16x16x32_bf16(a2h[m], b_l, acc2[m][n], 0, 0, 0);
        }
      }
    }
  }

  // ---- epilogue: h2 write + fused layer-2 node scores ----
#pragma unroll
  for (int m = 0; m < 2; m++) {
#pragma unroll
    for (int r = 0; r < 4; r++) {
      int grow = base + m * 16 + G * 4 + r;
      if (grow < N_NODES) {
#pragma unroll
        for (int n = 0; n < 4; n++)
          h2[(size_t)grow * OUT2 + n * 16 + lr] = acc2[m][n][r];
      }
      float sp = 0.f, dp = 0.f;
#pragma unroll
      for (int n = 0; n < 4; n++) {
        float v = acc2[m][n][r];
        sp += v * a2s[n * 16 + lr];
        dp += v * a2d[n * 16 + lr];
      }
#pragma unroll
      for (int o = 1; o < 16; o <<= 1) {
        sp += __shfl_xor(sp, o, 64);
        dp += __shfl_xor(dp, o, 64);
      }
      if (lr == 0 && grow < N_NODES) { as2[grow] = sp; ad2[grow] = dp; }
    }
  }
}

// ---- fused layer-2 softmax + aggregation + relu + FC head ------------------
__global__ void sm_agg2_final(const int* __restrict__ row_ptr, const int* __restrict__ csr_src,
                              const float* __restrict__ as_, const float* __restrict__ ad_,
                              const float* __restrict__ h2, const float* __restrict__ b2,
                              const float* __restrict__ fcW, const float* __restrict__ fcb,
                              float* __restrict__ out) {
  int wid = (blockIdx.x * blockDim.x + threadIdx.x) >> 6;
  int lane = threadIdx.x & 63;
  if (wid >= N_NODES) return;
  int beg = row_ptr[wid], end = row_ptr[wid + 1];
  int deg = end - beg;
  float adv = ad_[wid];
  float acc = 0.f;
  if (deg <= 64) {
    int s = 0; float sc = -3.4e38f;
    if (lane < deg) { s = csr_src[beg + lane]; sc = leaky(as_[s] + adv); }
    float m = wave_max(sc);
    float ex = (lane < deg) ? __expf(sc - m) : 0.f;
    float sum = wave_sum(ex);
    float a = ex / sum;
    int kk = 0;
    for (; kk + 8 <= deg; kk += 8) {
      float w0 = __shfl(a, kk, 64),     w1 = __shfl(a, kk + 1, 64);
      float w2 = __shfl(a, kk + 2, 64), w3 = __shfl(a, kk + 3, 64);
      float w4 = __shfl(a, kk + 4, 64), w5 = __shfl(a, kk + 5, 64);
      float w6 = __shfl(a, kk + 6, 64), w7 = __shfl(a, kk + 7, 64);
      int s0 = __shfl(s, kk, 64),     s1 = __shfl(s, kk + 1, 64);
      int s2 = __shfl(s, kk + 2, 64), s3 = __shfl(s, kk + 3, 64);
      int s4 = __shfl(s, kk + 4, 64), s5 = __shfl(s, kk + 5, 64);
      int s6 = __shfl(s, kk + 6, 64), s7 = __shfl(s, kk + 7, 64);
      float r0 = h2[(size_t)s0 * OUT2 + lane];
      float r1 = h2[(size_t)s1 * OUT2 + lane];
      float r2 = h2[(size_t)s2 * OUT2 + lane];
      float r3 = h2[(size_t)s3 * OUT2 + lane];
      float r4 = h2[(size_t)s4 * OUT2 + lane];
      float r5 = h2[(size_t)s5 * OUT2 + lane];
      float r6 = h2[(size_t)s6 * OUT2 + lane];
      float r7 = h2[(size_t)s7 * OUT2 + lane];
      acc += w0 * r0 + w1 * r1 + w2 * r2 + w3 * r3
           + w4 * r4 + w5 * r5 + w6 * r6 + w7 * r7;
    }
    for (; kk + 4 <= deg; kk += 4) {
      float w0 = __shfl(a, kk, 64),     w1 = __shfl(a, kk + 1, 64);
      float w2 = __shfl(a, kk + 2, 64), w3 = __shfl(a, kk + 3, 64);
      int s0 = __shfl(s, kk, 64),     s1 = __shfl(s, kk + 1, 64);
      int s2 = __shfl(s, kk + 2, 64), s3 = __shfl(s, kk + 3, 64);
      float r0 = h2[(size_t)s0 * OUT2 + lane];
      float r1 = h2[(size_t)s1 * OUT2 + lane];
      float r2 = h2[(size_t)s2 * OUT2 + lane];
      float r3 = h2[(size_t)s3 * OUT2 + lane];
      acc += w0 * r0 + w1 * r1 + w2 * r2 + w3 * r3;
    }
    for (; kk < deg; kk++) {
      float w = __shfl(a, kk, 64);
      int sv = __shfl(s, kk, 64);
      acc += w * h2[(size_t)sv * OUT2 + lane];
    }
  } else {
    float m = -3.4e38f;
    for (int k = beg + lane; k < end; k += 64)
      m = fmaxf(m, leaky(as_[csr_src[k]] + adv));
    m = wave_max(m);
    float sum = 0.f;
    for (int k = beg + lane; k < end; k += 64)
      sum += __expf(leaky(as_[csr_src[k]] + adv) - m);
    sum = wave_sum(sum);
    float inv = 1.f / sum;
    for (int k = beg; k < end; k++) {
      int sv = csr_src[k];
      float w = __expf(leaky(as_[sv] + adv) - m) * inv;
      acc += w * h2[(size_t)sv * OUT2 + lane];
    }
  }
  float v = fmaxf(acc + b2[lane], 0.f);
  float2 fw = ((const float2*)fcW)[lane];
  float f0 = wave_sum(v * fw.x);
  float f1 = wave_sum(v * fw.y);
  if (lane == 0) {
    out[(size_t)wid * 2 + 0] = f0 + fcb[0];
    out[(size_t)wid * 2 + 1] = f1 + fcb[1];
  }
}

extern "C" void kernel_launch(void* const* d_in, const int* in_sizes, int n_in,
                              void* d_out, int out_size, void* d_ws, size_t ws_size,
                              hipStream_t stream) {
  const float* x    = (const float*)d_in[0];
  const int*   ei   = (const int*)d_in[1];
  const float* W1   = (const float*)d_in[2];
  const float* a1s  = (const float*)d_in[3];
  const float* a1d  = (const float*)d_in[4];
  const float* b1   = (const float*)d_in[5];
  const float* W2   = (const float*)d_in[6];
  const float* a2s  = (const float*)d_in[7];
  const float* a2d  = (const float*)d_in[8];
  const float* b2   = (const float*)d_in[9];
  const float* fcW  = (const float*)d_in[10];
  const float* fcb  = (const float*)d_in[11];
  float* out = (float*)d_out;

  char* p = (char*)d_ws;
  float* xa    = (float*)p; p += (size_t)N_NODES * IN_C * 4;
  float* h2    = (float*)p; p += (size_t)N_NODES * OUT2 * 4;
  float* as1   = (float*)p; p += (size_t)N_NODES * 4;   // reused for layer-2 scores
  float* ad1   = (float*)p; p += (size_t)N_NODES * 4;
  float* w1s   = (float*)p; p += 256 * 4;
  float* w1d   = (float*)p; p += 256 * 4;
  int* row_ptr = (int*)p;   p += (size_t)(N_NODES + 4) * 4;
  int* deg     = (int*)p;   p += (size_t)N_NODES * 4;   // + cursor: one memset covers both
  int* cursor  = (int*)p;   p += (size_t)N_NODES * 4;
  int* bsum    = (int*)p;   p += 64 * 4;
  int* boff    = (int*)p;   p += 64 * 4;
  int* csr_src = (int*)p;   p += (size_t)E_TOT * 4;
  unsigned short* W1F = (unsigned short*)p; p += (size_t)128 * 2 * 64 * 8 * 2;  // 256KB
  unsigned short* W2F = (unsigned short*)p; p += (size_t)64 * 2 * 64 * 8 * 2;   // 128KB

  const int edge_blocks = (E_TOT + 255) / 256;
  const int node_wave_blocks = (N_NODES + 3) / 4;   // 4 waves per 256-thread block
  const int m_tiles128 = (N_NODES + 127) / 128;     // 391 blocks of 256 threads
  const int scan_blocks = (N_NODES + 1023) / 1024;  // 49

  // ---- CSR build + weight prep ----
  hipMemsetAsync(deg, 0, (size_t)N_NODES * 8, stream);   // zeros deg AND cursor
  count_deg<<<edge_blocks, 256, 0, stream>>>(ei, deg);
  scanA<<<scan_blocks, 1024, 0, stream>>>(deg, bsum);
  scanB<<<1, 64, 0, stream>>>(bsum, boff, scan_blocks);
  scanC<<<scan_blocks, 1024, 0, stream>>>(deg, boff, row_ptr);
  fill_csr<<<edge_blocks, 256, 0, stream>>>(ei, row_ptr, cursor, csr_src);
  prep_weights<<<80, 256, 0, stream>>>(W1, W2, a1s, a1d, W1F, W2F, w1s, w1d);

  // ---- layer 1: scores -> fused softmax+aggregate (input space) ----
  node_scores128<<<node_wave_blocks, 256, 0, stream>>>(x, w1s, w1d, as1, ad1);
  sm_agg1<<<node_wave_blocks, 256, 0, stream>>>(row_ptr, csr_src, as1, ad1, x, xa);

  // ---- fused gemm1+relu+gemm2+layer-2 scores (LDS-staged B, async) ----
  fused_gemm_mfma<<<m_tiles128, 256, 0, stream>>>(xa, W1F, b1, W2F,
                                                  a2s, a2d, h2, as1, ad1);

  // ---- layer 2: fused softmax+aggregate+relu+head ----
  sm_agg2_final<<<node_wave_blocks, 256, 0, stream>>>(row_ptr, csr_src, as1, ad1, h2, b2,
                                                      fcW, fcb, out);
}